// Round 1
// 341.690 us; speedup vs baseline: 1.3582x; 1.3582x over previous
//
#include <hip/hip_runtime.h>
#include <cstdint>
#include <cstddef>

typedef __bf16 bf16x8 __attribute__((ext_vector_type(8)));
typedef float floatx4 __attribute__((ext_vector_type(4)));

#define DEV static __device__ __forceinline__

DEV float bf2f(uint16_t u) {
    union { uint32_t i; float f; } x; x.i = ((uint32_t)u) << 16; return x.f;
}
DEV uint16_t f2bf(float f) {
    uint32_t u = __float_as_uint(f);
    uint32_t r = (u + 0x7FFFu + ((u >> 16) & 1u)) >> 16;   // RNE
    return (uint16_t)r;
}
DEV bf16x8 as_bf8(uint4 u) {
    union { uint4 u; bf16x8 b; } c; c.u = u; return c.b;
}
// async global->LDS, 16B per lane. LDS dest must be wave-uniform base (+lane*16 by HW).
DEV void g2l16(const void* g, void* l) {
    __builtin_amdgcn_global_load_lds(
        (const __attribute__((address_space(1))) void*)g,
        (__attribute__((address_space(3))) void*)l, 16, 0, 0);
}

union U16x8 { uint16_t h[8]; uint4 u; };

// ---------------- problem constants ----------------
constexpr int DIMC  = 384;
constexpr int HEADS = 12;
constexpr int IMH   = 56, IMW = 56;
constexpr int NTOK  = IMH * IMW;        // 3136
constexpr int BATCH = 16;
constexpr int MTOT  = BATCH * NTOK;     // 50176
constexpr int QKVLD = 3 * DIMC;         // 1152
constexpr int GK    = 384;              // K for both GEMMs

// ---------------- prep: fp32 -> bf16 (8 elems/thread) ----------------
__global__ __launch_bounds__(256) void cvt_bf16(const float* __restrict__ in,
                                                uint16_t* __restrict__ out)
{
    size_t i = ((size_t)blockIdx.x * 256 + threadIdx.x) * 8;
    float4 a = *(const float4*)(in + i);
    float4 b = *(const float4*)(in + i + 4);
    U16x8 t;
    t.h[0] = f2bf(a.x); t.h[1] = f2bf(a.y); t.h[2] = f2bf(a.z); t.h[3] = f2bf(a.w);
    t.h[4] = f2bf(b.x); t.h[5] = f2bf(b.y); t.h[6] = f2bf(b.z); t.h[7] = f2bf(b.w);
    *(uint4*)(out + i) = t.u;
}

// ---------------- prep: in[R][C] fp32 -> out[C][R] bf16 ----------------
__global__ __launch_bounds__(256) void transpose_cvt(const float* __restrict__ in,
                                                     uint16_t* __restrict__ out,
                                                     int R, int C)
{
    int idx = blockIdx.x * 256 + threadIdx.x;   // output-linear: idx = c*R + r
    int r = idx % R, c = idx / R;
    out[idx] = f2bf(in[(size_t)r * C + c]);
}

// ---------------- GEMM (m97 structure): C[M,N] = A[M,K=384] @ Bt[N,K]^T ----
// A bf16 [M][384], Bt bf16 [N][384]; C bf16 (CF32=false) or fp32 (+bias).
template<bool CF32>
__global__ __launch_bounds__(256) void gemm_bt(const uint16_t* __restrict__ A,
                                               const uint16_t* __restrict__ Bt,
                                               const float* __restrict__ bias,
                                               void* __restrict__ Cptr,
                                               int N)
{
    __shared__ __align__(16) uint16_t sA[128 * 32];
    __shared__ __align__(16) uint16_t sB[128 * 32];

    const int t    = threadIdx.x;
    const int bm   = blockIdx.x, bn = blockIdx.y;
    const int wave = t >> 6, lane = t & 63;
    const int wm   = (wave >> 1) * 64, wn = (wave & 1) * 64;
    const int lr   = lane & 15, quad = lane >> 4;

    // staging: thread t covers row t>>2 (call1) / 64+(t>>2) (call2), 8 elems at (t&3)*8
    const uint16_t* Ag = A  + (size_t)(bm * 128 + (t >> 2)) * GK + (t & 3) * 8;
    const uint16_t* Bg = Bt + (size_t)(bn * 128 + (t >> 2)) * GK + (t & 3) * 8;
    uint16_t* lA1 = sA + wave * 512;
    uint16_t* lA2 = sA + 2048 + wave * 512;
    uint16_t* lB1 = sB + wave * 512;
    uint16_t* lB2 = sB + 2048 + wave * 512;

    floatx4 acc[4][4] = {};

    #pragma unroll
    for (int k0 = 0; k0 < GK; k0 += 32) {
        __syncthreads();
        g2l16(Ag + k0, lA1);
        g2l16(Ag + (size_t)64 * GK + k0, lA2);
        g2l16(Bg + k0, lB1);
        g2l16(Bg + (size_t)64 * GK + k0, lB2);
        __syncthreads();   // compiler emits s_waitcnt vmcnt(0) before barrier

        bf16x8 af[4], bfr[4];
        #pragma unroll
        for (int mt = 0; mt < 4; ++mt)
            af[mt] = *(const bf16x8*)&sA[(wm + mt * 16 + lr) * 32 + quad * 8];
        #pragma unroll
        for (int nt = 0; nt < 4; ++nt)
            bfr[nt] = *(const bf16x8*)&sB[(wn + nt * 16 + lr) * 32 + quad * 8];
        #pragma unroll
        for (int mt = 0; mt < 4; ++mt)
            #pragma unroll
            for (int nt = 0; nt < 4; ++nt)
                acc[mt][nt] = __builtin_amdgcn_mfma_f32_16x16x32_bf16(
                    af[mt], bfr[nt], acc[mt][nt], 0, 0, 0);
    }

    // epilogue: C/D layout col=lane&15, row=quad*4+reg
    #pragma unroll
    for (int mt = 0; mt < 4; ++mt) {
        #pragma unroll
        for (int nt = 0; nt < 4; ++nt) {
            int gc = bn * 128 + wn + nt * 16 + lr;
            float bv = bias ? bias[gc] : 0.0f;
            int gr0 = bm * 128 + wm + mt * 16 + quad * 4;
            #pragma unroll
            for (int i = 0; i < 4; ++i) {
                if constexpr (CF32) {
                    ((float*)Cptr)[(size_t)(gr0 + i) * N + gc] = acc[mt][nt][i] + bv;
                } else {
                    ((uint16_t*)Cptr)[(size_t)(gr0 + i) * N + gc] = f2bf(acc[mt][nt][i] + bv);
                }
            }
        }
    }
}

// ---------------- MFMA windowed attention ----------------
// one wave per (b, window, head); 2 waves / 128-thread block.
constexpr int PLD = 72;   // padded row stride (bf16 elems)

__global__ __launch_bounds__(128) void attn_mfma(const uint16_t* __restrict__ qkv,
                                                 uint16_t* __restrict__ y)
{
    __shared__ uint16_t lds[2][(64 + 32) * PLD];

    const int wave = threadIdx.x >> 6;
    const int lane = threadIdx.x & 63;
    const int unit = blockIdx.x * 2 + wave;          // 0..12287
    const int h  = unit % HEADS;
    const int w  = (unit / HEADS) & 63;
    const int b  = unit / (HEADS * 64);
    const int wy = w >> 3, wx = w & 7;
    const int lr = lane & 15, quad = lane >> 4;

    uint16_t* Pbuf = lds[wave];
    uint16_t* Vt   = lds[wave] + 64 * PLD;

    auto rowbase = [&](int i, int which) -> const uint16_t* {
        int py = i / 7, px = i % 7;
        int n = (wy * 7 + py) * IMW + wx * 7 + px;
        return qkv + (size_t)(b * NTOK + n) * QKVLD + which * DIMC + h * 32;
    };

    uint4 qf[4], kf[4];
    #pragma unroll
    for (int tm = 0; tm < 4; ++tm) {
        int i = tm * 16 + lr;
        if (i < 49) {
            qf[tm] = *(const uint4*)(rowbase(i, 0) + quad * 8);
            kf[tm] = *(const uint4*)(rowbase(i, 1) + quad * 8);
        } else {
            qf[tm] = uint4{0, 0, 0, 0};
            kf[tm] = uint4{0, 0, 0, 0};
        }
    }

    {   // stage V transposed: Vt[d][j]
        int j = lane;
        uint16_t vrow[32];
        if (j < 49) {
            const uint16_t* vr = rowbase(j, 2);
            #pragma unroll
            for (int p = 0; p < 4; ++p) {
                U16x8 tmp; tmp.u = *(const uint4*)(vr + p * 8);
                #pragma unroll
                for (int q = 0; q < 8; ++q) vrow[p * 8 + q] = tmp.h[q];
            }
        } else {
            #pragma unroll
            for (int d = 0; d < 32; ++d) vrow[d] = 0;
        }
        #pragma unroll
        for (int d = 0; d < 32; ++d) Vt[d * PLD + j] = vrow[d];
    }

    floatx4 S[4][4] = {};
    #pragma unroll
    for (int tm = 0; tm < 4; ++tm)
        #pragma unroll
        for (int tn = 0; tn < 4; ++tn)
            S[tm][tn] = __builtin_amdgcn_mfma_f32_16x16x32_bf16(
                as_bf8(qf[tm]), as_bf8(kf[tn]), S[tm][tn], 0, 0, 0);

    const float scale = 0.17677669529663687f;  // 32^-0.5
    const bool v3 = (lr == 0);
    #pragma unroll
    for (int tm = 0; tm < 4; ++tm) {
        #pragma unroll
        for (int i = 0; i < 4; ++i) {
            float e0 = __expf(S[tm][0][i] * scale);
            float e1 = __expf(S[tm][1][i] * scale);
            float e2 = __expf(S[tm][2][i] * scale);
            float e3 = v3 ? __expf(S[tm][3][i] * scale) : 0.0f;
            float s = e0 + e1 + e2 + e3;
            #pragma unroll
            for (int d = 1; d < 16; d <<= 1) s += __shfl_xor(s, d);
            float inv = 1.0f / s;
            int row = tm * 16 + quad * 4 + i;
            Pbuf[row * PLD + lr]      = f2bf(e0 * inv);
            Pbuf[row * PLD + 16 + lr] = f2bf(e1 * inv);
            Pbuf[row * PLD + 32 + lr] = f2bf(e2 * inv);
            Pbuf[row * PLD + 48 + lr] = f2bf(e3 * inv);
        }
    }

    floatx4 O[4][2] = {};
    #pragma unroll
    for (int kk = 0; kk < 2; ++kk) {
        bf16x8 pf[4], vf[2];
        #pragma unroll
        for (int tm = 0; tm < 4; ++tm)
            pf[tm] = *(const bf16x8*)&Pbuf[(tm * 16 + lr) * PLD + kk * 32 + quad * 8];
        #pragma unroll
        for (int tn = 0; tn < 2; ++tn)
            vf[tn] = *(const bf16x8*)&Vt[(tn * 16 + lr) * PLD + kk * 32 + quad * 8];
        #pragma unroll
        for (int tm = 0; tm < 4; ++tm)
            #pragma unroll
            for (int tn = 0; tn < 2; ++tn)
                O[tm][tn] = __builtin_amdgcn_mfma_f32_16x16x32_bf16(
                    pf[tm], vf[tn], O[tm][tn], 0, 0, 0);
    }

    #pragma unroll
    for (int tm = 0; tm < 4; ++tm) {
        #pragma unroll
        for (int i = 0; i < 4; ++i) {
            int r = tm * 16 + quad * 4 + i;
            if (r < 49) {
                int py = r / 7, px = r % 7;
                int n = (wy * 7 + py) * IMW + wx * 7 + px;
                uint16_t* dst = y + (size_t)(b * NTOK + n) * DIMC + h * 32;
                dst[lr]      = f2bf(O[tm][0][i]);
                dst[16 + lr] = f2bf(O[tm][1][i]);
            }
        }
    }
}

// ---------------- depthwise 3x3 conv on v, accumulate into y (bf16) --------
// Vectorized: 8 channels per thread. uint4 (bf16x8) v loads, float4 weight
// loads (13.8 KB table, L1-resident), uint4 RMW on y.
__global__ __launch_bounds__(256) void conv_kernel(const uint16_t* __restrict__ qkv,
                                                   const float* __restrict__ wconv,
                                                   const float* __restrict__ bconv,
                                                   uint16_t* __restrict__ y)
{
    constexpr int C8 = DIMC / 8;                      // 48 vector-chunks per token
    size_t idx = (size_t)blockIdx.x * 256 + threadIdx.x;   // MTOT*C8 total
    int c8  = (int)(idx % C8);
    int rem = (int)(idx / C8);
    int n   = rem % NTOK;
    int b   = rem / NTOK;
    int c   = c8 * 8;
    int y0 = n / IMW, x0 = n % IMW;

    float acc[8];
    {
        float4 b0 = *(const float4*)(bconv + c);
        float4 b1 = *(const float4*)(bconv + c + 4);
        acc[0] = b0.x; acc[1] = b0.y; acc[2] = b0.z; acc[3] = b0.w;
        acc[4] = b1.x; acc[5] = b1.y; acc[6] = b1.z; acc[7] = b1.w;
    }

    const uint16_t* vbase = qkv + 2 * DIMC + c;
    #pragma unroll
    for (int ky = 0; ky < 3; ++ky) {
        int yy = y0 + ky - 1;
        if (yy < 0 || yy >= IMH) continue;
        #pragma unroll
        for (int kx = 0; kx < 3; ++kx) {
            int xx = x0 + kx - 1;
            if (xx < 0 || xx >= IMW) continue;
            U16x8 v;
            v.u = *(const uint4*)(vbase + (size_t)(b * NTOK + yy * IMW + xx) * QKVLD);
            const float* wp = wconv + (ky * 3 + kx) * DIMC + c;
            float4 w0 = *(const float4*)(wp);
            float4 w1 = *(const float4*)(wp + 4);
            acc[0] += bf2f(v.h[0]) * w0.x;
            acc[1] += bf2f(v.h[1]) * w0.y;
            acc[2] += bf2f(v.h[2]) * w0.z;
            acc[3] += bf2f(v.h[3]) * w0.w;
            acc[4] += bf2f(v.h[4]) * w1.x;
            acc[5] += bf2f(v.h[5]) * w1.y;
            acc[6] += bf2f(v.h[6]) * w1.z;
            acc[7] += bf2f(v.h[7]) * w1.w;
        }
    }

    uint16_t* yp = y + (size_t)rem * DIMC + c;
    U16x8 yo; yo.u = *(const uint4*)yp;
    #pragma unroll
    for (int j = 0; j < 8; ++j) yo.h[j] = f2bf(bf2f(yo.h[j]) + acc[j]);
    *(uint4*)yp = yo.u;
}

// ---------------- launch ----------------
extern "C" void kernel_launch(void* const* d_in, const int* in_sizes, int n_in,
                              void* d_out, int out_size, void* d_ws, size_t ws_size,
                              hipStream_t stream)
{
    const float* x      = (const float*)d_in[0];
    const float* w_qkv  = (const float*)d_in[1];
    const float* w_proj = (const float*)d_in[2];
    const float* b_proj = (const float*)d_in[3];
    const float* w_conv = (const float*)d_in[4];
    const float* b_conv = (const float*)d_in[5];
    float* out = (float*)d_out;

    // ws layout (155.3 MB):
    //  [0, 115605504)              qkv bf16 (50176 x 1152)
    //  [115605504, +38535168)      xb bf16 (50176 x 384), reused as y bf16 after GEMM1
    //  then wqkvT bf16 (1152x384), wprojT bf16 (384x384)
    char* ws = (char*)d_ws;
    uint16_t* qkv    = (uint16_t*)ws;
    uint16_t* xb     = (uint16_t*)(ws + 115605504);
    uint16_t* yb     = xb;  // alias: xb dead after GEMM1
    uint16_t* wqkvT  = (uint16_t*)(ws + 115605504 + 38535168);
    uint16_t* wprojT = wqkvT + QKVLD * GK;

    // prep
    cvt_bf16<<<dim3((MTOT * DIMC) / (8 * 256)), 256, 0, stream>>>(x, xb);
    transpose_cvt<<<dim3((GK * QKVLD) / 256), 256, 0, stream>>>(w_qkv, wqkvT, GK, QKVLD);
    transpose_cvt<<<dim3((GK * DIMC) / 256), 256, 0, stream>>>(w_proj, wprojT, GK, DIMC);

    // 1) qkv = xb @ w_qkv   (M=50176, N=1152), bf16 out
    gemm_bt<false><<<dim3(MTOT / 128, QKVLD / 128), 256, 0, stream>>>(
        xb, wqkvT, nullptr, qkv, QKVLD);

    // 2) MFMA windowed attention -> y (bf16)
    attn_mfma<<<dim3(BATCH * 64 * HEADS / 2), 128, 0, stream>>>(qkv, yb);

    // 3) depthwise conv on v, y += v_lim (8 channels/thread, vectorized)
    conv_kernel<<<dim3((MTOT * (DIMC / 8)) / 256), 256, 0, stream>>>(
        qkv, w_conv, b_conv, yb);

    // 4) out = y @ w_proj + b_proj (M=50176, N=384), fp32 out
    gemm_bt<true><<<dim3(MTOT / 128, DIMC / 128), 256, 0, stream>>>(
        yb, wprojT, b_proj, out, DIMC);
}

// Round 2
// 327.595 us; speedup vs baseline: 1.4167x; 1.0430x over previous
//
#include <hip/hip_runtime.h>
#include <cstdint>
#include <cstddef>

typedef __bf16 bf16x8 __attribute__((ext_vector_type(8)));
typedef float floatx4 __attribute__((ext_vector_type(4)));

#define DEV static __device__ __forceinline__

DEV float bf2f(uint16_t u) {
    union { uint32_t i; float f; } x; x.i = ((uint32_t)u) << 16; return x.f;
}
DEV uint16_t f2bf(float f) {
    uint32_t u = __float_as_uint(f);
    uint32_t r = (u + 0x7FFFu + ((u >> 16) & 1u)) >> 16;   // RNE
    return (uint16_t)r;
}
DEV bf16x8 as_bf8(uint4 u) {
    union { uint4 u; bf16x8 b; } c; c.u = u; return c.b;
}
// async global->LDS, 16B per lane. LDS dest must be wave-uniform base (+lane*16 by HW).
DEV void g2l16(const void* g, void* l) {
    __builtin_amdgcn_global_load_lds(
        (const __attribute__((address_space(1))) void*)g,
        (__attribute__((address_space(3))) void*)l, 16, 0, 0);
}

union U16x8 { uint16_t h[8]; uint4 u; };

// ---------------- problem constants ----------------
constexpr int DIMC  = 384;
constexpr int HEADS = 12;
constexpr int IMH   = 56, IMW = 56;
constexpr int NTOK  = IMH * IMW;        // 3136
constexpr int BATCH = 16;
constexpr int MTOT  = BATCH * NTOK;     // 50176
constexpr int QKVLD = 3 * DIMC;         // 1152
constexpr int GK    = 384;              // K for both GEMMs

// ---------------- prep: fp32 -> bf16 (8 elems/thread) ----------------
__global__ __launch_bounds__(256) void cvt_bf16(const float* __restrict__ in,
                                                uint16_t* __restrict__ out)
{
    size_t i = ((size_t)blockIdx.x * 256 + threadIdx.x) * 8;
    float4 a = *(const float4*)(in + i);
    float4 b = *(const float4*)(in + i + 4);
    U16x8 t;
    t.h[0] = f2bf(a.x); t.h[1] = f2bf(a.y); t.h[2] = f2bf(a.z); t.h[3] = f2bf(a.w);
    t.h[4] = f2bf(b.x); t.h[5] = f2bf(b.y); t.h[6] = f2bf(b.z); t.h[7] = f2bf(b.w);
    *(uint4*)(out + i) = t.u;
}

// ---------------- prep: in[R][C] fp32 -> out[C][R] bf16 ----------------
__global__ __launch_bounds__(256) void transpose_cvt(const float* __restrict__ in,
                                                     uint16_t* __restrict__ out,
                                                     int R, int C)
{
    int idx = blockIdx.x * 256 + threadIdx.x;   // output-linear: idx = c*R + r
    int r = idx % R, c = idx / R;
    out[idx] = f2bf(in[(size_t)r * C + c]);
}

// ---------------- GEMM: C[M,N] = A[M,K=384] @ Bt[N,K]^T ----
// A bf16 [M][384], Bt bf16 [N][384]; C bf16 (CF32=false) or fp32 (+bias).
// 2-phase double-buffered pipeline (T3-minimum): STAGE(next) issued BEFORE
// ds_read+MFMA(cur), one vmcnt-drain+barrier per K-step -> HBM latency hides
// under compute instead of being serially exposed.
// 1D grid with M-supertile-8 swizzle: round-robin block->XCD gives each XCD
// ONE A-panel per chunk, reused across all N-tiles (A fetched ~1x not ~2.2x).
template<bool CF32>
__global__ __launch_bounds__(256) void gemm_bt(const uint16_t* __restrict__ A,
                                               const uint16_t* __restrict__ Bt,
                                               const float* __restrict__ bias,
                                               void* __restrict__ Cptr,
                                               int N)
{
    __shared__ __align__(16) uint16_t sA[2][128 * 32];
    __shared__ __align__(16) uint16_t sB[2][128 * 32];

    const int t    = threadIdx.x;
    const int NB   = N >> 7;                       // N-tiles (9 or 3)
    const int bid  = blockIdx.x;
    const int chunk = bid / (8 * NB);
    const int r     = bid % (8 * NB);
    const int bm    = chunk * 8 + (r & 7);
    const int bn    = r >> 3;
    const int wave = t >> 6, lane = t & 63;
    const int wm   = (wave >> 1) * 64, wn = (wave & 1) * 64;
    const int lr   = lane & 15, quad = lane >> 4;

    // staging: thread t covers row t>>2 (call1) / 64+(t>>2) (call2), 8 elems at (t&3)*8
    const uint16_t* Ag = A  + (size_t)(bm * 128 + (t >> 2)) * GK + (t & 3) * 8;
    const uint16_t* Bg = Bt + (size_t)(bn * 128 + (t >> 2)) * GK + (t & 3) * 8;

    auto stage = [&](int buf, int k0) {
        g2l16(Ag + k0, sA[buf] + wave * 512);
        g2l16(Ag + (size_t)64 * GK + k0, sA[buf] + 2048 + wave * 512);
        g2l16(Bg + k0, sB[buf] + wave * 512);
        g2l16(Bg + (size_t)64 * GK + k0, sB[buf] + 2048 + wave * 512);
    };

    floatx4 acc[4][4] = {};

    stage(0, 0);
    __syncthreads();   // drain vmcnt(0): buf0 ready

    #pragma unroll
    for (int ks = 0; ks < 12; ++ks) {
        const int cur = ks & 1;
        if (ks < 11) stage(cur ^ 1, (ks + 1) * 32);   // prefetch next tile

        bf16x8 af[4], bfr[4];
        #pragma unroll
        for (int mt = 0; mt < 4; ++mt)
            af[mt] = *(const bf16x8*)&sA[cur][(wm + mt * 16 + lr) * 32 + quad * 8];
        #pragma unroll
        for (int nt = 0; nt < 4; ++nt)
            bfr[nt] = *(const bf16x8*)&sB[cur][(wn + nt * 16 + lr) * 32 + quad * 8];
        #pragma unroll
        for (int mt = 0; mt < 4; ++mt)
            #pragma unroll
            for (int nt = 0; nt < 4; ++nt)
                acc[mt][nt] = __builtin_amdgcn_mfma_f32_16x16x32_bf16(
                    af[mt], bfr[nt], acc[mt][nt], 0, 0, 0);

        // safe to overwrite buf[cur] next iter: all waves past this barrier
        // have consumed their ds_reads (lgkm drained before MFMA use).
        __syncthreads();
    }

    // epilogue: C/D layout col=lane&15, row=quad*4+reg
    #pragma unroll
    for (int mt = 0; mt < 4; ++mt) {
        #pragma unroll
        for (int nt = 0; nt < 4; ++nt) {
            int gc = bn * 128 + wn + nt * 16 + lr;
            float bv = bias ? bias[gc] : 0.0f;
            int gr0 = bm * 128 + wm + mt * 16 + quad * 4;
            #pragma unroll
            for (int i = 0; i < 4; ++i) {
                if constexpr (CF32) {
                    ((float*)Cptr)[(size_t)(gr0 + i) * N + gc] = acc[mt][nt][i] + bv;
                } else {
                    ((uint16_t*)Cptr)[(size_t)(gr0 + i) * N + gc] = f2bf(acc[mt][nt][i] + bv);
                }
            }
        }
    }
}

// ---------------- MFMA windowed attention ----------------
// one wave per (b, window, head); 2 waves / 128-thread block.
constexpr int PLD = 72;   // padded row stride (bf16 elems)

__global__ __launch_bounds__(128) void attn_mfma(const uint16_t* __restrict__ qkv,
                                                 uint16_t* __restrict__ y)
{
    __shared__ uint16_t lds[2][(64 + 32) * PLD];

    const int wave = threadIdx.x >> 6;
    const int lane = threadIdx.x & 63;
    const int unit = blockIdx.x * 2 + wave;          // 0..12287
    const int h  = unit % HEADS;
    const int w  = (unit / HEADS) & 63;
    const int b  = unit / (HEADS * 64);
    const int wy = w >> 3, wx = w & 7;
    const int lr = lane & 15, quad = lane >> 4;

    uint16_t* Pbuf = lds[wave];
    uint16_t* Vt   = lds[wave] + 64 * PLD;

    auto rowbase = [&](int i, int which) -> const uint16_t* {
        int py = i / 7, px = i % 7;
        int n = (wy * 7 + py) * IMW + wx * 7 + px;
        return qkv + (size_t)(b * NTOK + n) * QKVLD + which * DIMC + h * 32;
    };

    uint4 qf[4], kf[4];
    #pragma unroll
    for (int tm = 0; tm < 4; ++tm) {
        int i = tm * 16 + lr;
        if (i < 49) {
            qf[tm] = *(const uint4*)(rowbase(i, 0) + quad * 8);
            kf[tm] = *(const uint4*)(rowbase(i, 1) + quad * 8);
        } else {
            qf[tm] = uint4{0, 0, 0, 0};
            kf[tm] = uint4{0, 0, 0, 0};
        }
    }

    {   // stage V transposed: Vt[d][j]
        int j = lane;
        uint16_t vrow[32];
        if (j < 49) {
            const uint16_t* vr = rowbase(j, 2);
            #pragma unroll
            for (int p = 0; p < 4; ++p) {
                U16x8 tmp; tmp.u = *(const uint4*)(vr + p * 8);
                #pragma unroll
                for (int q = 0; q < 8; ++q) vrow[p * 8 + q] = tmp.h[q];
            }
        } else {
            #pragma unroll
            for (int d = 0; d < 32; ++d) vrow[d] = 0;
        }
        #pragma unroll
        for (int d = 0; d < 32; ++d) Vt[d * PLD + j] = vrow[d];
    }

    floatx4 S[4][4] = {};
    #pragma unroll
    for (int tm = 0; tm < 4; ++tm)
        #pragma unroll
        for (int tn = 0; tn < 4; ++tn)
            S[tm][tn] = __builtin_amdgcn_mfma_f32_16x16x32_bf16(
                as_bf8(qf[tm]), as_bf8(kf[tn]), S[tm][tn], 0, 0, 0);

    const float scale = 0.17677669529663687f;  // 32^-0.5
    const bool v3 = (lr == 0);
    #pragma unroll
    for (int tm = 0; tm < 4; ++tm) {
        #pragma unroll
        for (int i = 0; i < 4; ++i) {
            float e0 = __expf(S[tm][0][i] * scale);
            float e1 = __expf(S[tm][1][i] * scale);
            float e2 = __expf(S[tm][2][i] * scale);
            float e3 = v3 ? __expf(S[tm][3][i] * scale) : 0.0f;
            float s = e0 + e1 + e2 + e3;
            #pragma unroll
            for (int d = 1; d < 16; d <<= 1) s += __shfl_xor(s, d);
            float inv = 1.0f / s;
            int row = tm * 16 + quad * 4 + i;
            Pbuf[row * PLD + lr]      = f2bf(e0 * inv);
            Pbuf[row * PLD + 16 + lr] = f2bf(e1 * inv);
            Pbuf[row * PLD + 32 + lr] = f2bf(e2 * inv);
            Pbuf[row * PLD + 48 + lr] = f2bf(e3 * inv);
        }
    }

    floatx4 O[4][2] = {};
    #pragma unroll
    for (int kk = 0; kk < 2; ++kk) {
        bf16x8 pf[4], vf[2];
        #pragma unroll
        for (int tm = 0; tm < 4; ++tm)
            pf[tm] = *(const bf16x8*)&Pbuf[(tm * 16 + lr) * PLD + kk * 32 + quad * 8];
        #pragma unroll
        for (int tn = 0; tn < 2; ++tn)
            vf[tn] = *(const bf16x8*)&Vt[(tn * 16 + lr) * PLD + kk * 32 + quad * 8];
        #pragma unroll
        for (int tm = 0; tm < 4; ++tm)
            #pragma unroll
            for (int tn = 0; tn < 2; ++tn)
                O[tm][tn] = __builtin_amdgcn_mfma_f32_16x16x32_bf16(
                    pf[tm], vf[tn], O[tm][tn], 0, 0, 0);
    }

    #pragma unroll
    for (int tm = 0; tm < 4; ++tm) {
        #pragma unroll
        for (int i = 0; i < 4; ++i) {
            int r = tm * 16 + quad * 4 + i;
            if (r < 49) {
                int py = r / 7, px = r % 7;
                int n = (wy * 7 + py) * IMW + wx * 7 + px;
                uint16_t* dst = y + (size_t)(b * NTOK + n) * DIMC + h * 32;
                dst[lr]      = f2bf(O[tm][0][i]);
                dst[16 + lr] = f2bf(O[tm][1][i]);
            }
        }
    }
}

// ---------------- depthwise 3x3 conv on v, accumulate into y (bf16) --------
// Vectorized: 8 channels per thread. uint4 (bf16x8) v loads, float4 weight
// loads (13.8 KB table, L1-resident), uint4 RMW on y.
__global__ __launch_bounds__(256) void conv_kernel(const uint16_t* __restrict__ qkv,
                                                   const float* __restrict__ wconv,
                                                   const float* __restrict__ bconv,
                                                   uint16_t* __restrict__ y)
{
    constexpr int C8 = DIMC / 8;                      // 48 vector-chunks per token
    size_t idx = (size_t)blockIdx.x * 256 + threadIdx.x;   // MTOT*C8 total
    int c8  = (int)(idx % C8);
    int rem = (int)(idx / C8);
    int n   = rem % NTOK;
    int b   = rem / NTOK;
    int c   = c8 * 8;
    int y0 = n / IMW, x0 = n % IMW;

    float acc[8];
    {
        float4 b0 = *(const float4*)(bconv + c);
        float4 b1 = *(const float4*)(bconv + c + 4);
        acc[0] = b0.x; acc[1] = b0.y; acc[2] = b0.z; acc[3] = b0.w;
        acc[4] = b1.x; acc[5] = b1.y; acc[6] = b1.z; acc[7] = b1.w;
    }

    const uint16_t* vbase = qkv + 2 * DIMC + c;
    #pragma unroll
    for (int ky = 0; ky < 3; ++ky) {
        int yy = y0 + ky - 1;
        if (yy < 0 || yy >= IMH) continue;
        #pragma unroll
        for (int kx = 0; kx < 3; ++kx) {
            int xx = x0 + kx - 1;
            if (xx < 0 || xx >= IMW) continue;
            U16x8 v;
            v.u = *(const uint4*)(vbase + (size_t)(b * NTOK + yy * IMW + xx) * QKVLD);
            const float* wp = wconv + (ky * 3 + kx) * DIMC + c;
            float4 w0 = *(const float4*)(wp);
            float4 w1 = *(const float4*)(wp + 4);
            acc[0] += bf2f(v.h[0]) * w0.x;
            acc[1] += bf2f(v.h[1]) * w0.y;
            acc[2] += bf2f(v.h[2]) * w0.z;
            acc[3] += bf2f(v.h[3]) * w0.w;
            acc[4] += bf2f(v.h[4]) * w1.x;
            acc[5] += bf2f(v.h[5]) * w1.y;
            acc[6] += bf2f(v.h[6]) * w1.z;
            acc[7] += bf2f(v.h[7]) * w1.w;
        }
    }

    uint16_t* yp = y + (size_t)rem * DIMC + c;
    U16x8 yo; yo.u = *(const uint4*)yp;
    #pragma unroll
    for (int j = 0; j < 8; ++j) yo.h[j] = f2bf(bf2f(yo.h[j]) + acc[j]);
    *(uint4*)yp = yo.u;
}

// ---------------- launch ----------------
extern "C" void kernel_launch(void* const* d_in, const int* in_sizes, int n_in,
                              void* d_out, int out_size, void* d_ws, size_t ws_size,
                              hipStream_t stream)
{
    const float* x      = (const float*)d_in[0];
    const float* w_qkv  = (const float*)d_in[1];
    const float* w_proj = (const float*)d_in[2];
    const float* b_proj = (const float*)d_in[3];
    const float* w_conv = (const float*)d_in[4];
    const float* b_conv = (const float*)d_in[5];
    float* out = (float*)d_out;

    // ws layout (155.3 MB):
    //  [0, 115605504)              qkv bf16 (50176 x 1152)
    //  [115605504, +38535168)      xb bf16 (50176 x 384), reused as y bf16 after GEMM1
    //  then wqkvT bf16 (1152x384), wprojT bf16 (384x384)
    char* ws = (char*)d_ws;
    uint16_t* qkv    = (uint16_t*)ws;
    uint16_t* xb     = (uint16_t*)(ws + 115605504);
    uint16_t* yb     = xb;  // alias: xb dead after GEMM1
    uint16_t* wqkvT  = (uint16_t*)(ws + 115605504 + 38535168);
    uint16_t* wprojT = wqkvT + QKVLD * GK;

    // prep
    cvt_bf16<<<dim3((MTOT * DIMC) / (8 * 256)), 256, 0, stream>>>(x, xb);
    transpose_cvt<<<dim3((GK * QKVLD) / 256), 256, 0, stream>>>(w_qkv, wqkvT, GK, QKVLD);
    transpose_cvt<<<dim3((GK * DIMC) / 256), 256, 0, stream>>>(w_proj, wprojT, GK, DIMC);

    // 1) qkv = xb @ w_qkv   (M=50176, N=1152), bf16 out  [1D grid, supertiled]
    gemm_bt<false><<<dim3((MTOT / 128) * (QKVLD / 128)), 256, 0, stream>>>(
        xb, wqkvT, nullptr, qkv, QKVLD);

    // 2) MFMA windowed attention -> y (bf16)
    attn_mfma<<<dim3(BATCH * 64 * HEADS / 2), 128, 0, stream>>>(qkv, yb);

    // 3) depthwise conv on v, y += v_lim (8 channels/thread, vectorized)
    conv_kernel<<<dim3((MTOT * (DIMC / 8)) / 256), 256, 0, stream>>>(
        qkv, w_conv, b_conv, yb);

    // 4) out = y @ w_proj + b_proj (M=50176, N=384), fp32 out  [1D grid]
    gemm_bt<true><<<dim3((MTOT / 128) * (DIMC / 128)), 256, 0, stream>>>(
        yb, wprojT, b_proj, out, DIMC);
}

// Round 3
// 320.170 us; speedup vs baseline: 1.4495x; 1.0232x over previous
//
#include <hip/hip_runtime.h>
#include <cstdint>
#include <cstddef>

typedef __bf16 bf16x8 __attribute__((ext_vector_type(8)));
typedef float floatx4 __attribute__((ext_vector_type(4)));

#define DEV static __device__ __forceinline__

DEV float bf2f(uint16_t u) {
    union { uint32_t i; float f; } x; x.i = ((uint32_t)u) << 16; return x.f;
}
DEV uint16_t f2bf(float f) {
    uint32_t u = __float_as_uint(f);
    uint32_t r = (u + 0x7FFFu + ((u >> 16) & 1u)) >> 16;   // RNE
    return (uint16_t)r;
}
DEV bf16x8 as_bf8(uint4 u) {
    union { uint4 u; bf16x8 b; } c; c.u = u; return c.b;
}
// async global->LDS, 16B per lane. LDS dest must be wave-uniform base (+lane*16 by HW).
DEV void g2l16(const void* g, void* l) {
    __builtin_amdgcn_global_load_lds(
        (const __attribute__((address_space(1))) void*)g,
        (__attribute__((address_space(3))) void*)l, 16, 0, 0);
}

union U16x8 { uint16_t h[8]; uint4 u; };

// ---------------- problem constants ----------------
constexpr int DIMC  = 384;
constexpr int HEADS = 12;
constexpr int IMH   = 56, IMW = 56;
constexpr int NTOK  = IMH * IMW;        // 3136
constexpr int BATCH = 16;
constexpr int MTOT  = BATCH * NTOK;     // 50176
constexpr int QKVLD = 3 * DIMC;         // 1152
constexpr int GK    = 384;              // K for both GEMMs

// ---------------- prep: fp32 -> bf16 (8 elems/thread) ----------------
__global__ __launch_bounds__(256) void cvt_bf16(const float* __restrict__ in,
                                                uint16_t* __restrict__ out)
{
    size_t i = ((size_t)blockIdx.x * 256 + threadIdx.x) * 8;
    float4 a = *(const float4*)(in + i);
    float4 b = *(const float4*)(in + i + 4);
    U16x8 t;
    t.h[0] = f2bf(a.x); t.h[1] = f2bf(a.y); t.h[2] = f2bf(a.z); t.h[3] = f2bf(a.w);
    t.h[4] = f2bf(b.x); t.h[5] = f2bf(b.y); t.h[6] = f2bf(b.z); t.h[7] = f2bf(b.w);
    *(uint4*)(out + i) = t.u;
}

// ---------------- prep: in[R][C] fp32 -> out[C][R] bf16 ----------------
__global__ __launch_bounds__(256) void transpose_cvt(const float* __restrict__ in,
                                                     uint16_t* __restrict__ out,
                                                     int R, int C)
{
    int idx = blockIdx.x * 256 + threadIdx.x;   // output-linear: idx = c*R + r
    int r = idx % R, c = idx / R;
    out[idx] = f2bf(in[(size_t)r * C + c]);
}

// ---------------- GEMM: C[M,N] = A[M,K=384] @ Bt[N,K]^T ----
// 2-phase double-buffered pipeline; 1D grid with M-supertile-8 XCD swizzle.
template<bool CF32>
__global__ __launch_bounds__(256) void gemm_bt(const uint16_t* __restrict__ A,
                                               const uint16_t* __restrict__ Bt,
                                               const float* __restrict__ bias,
                                               void* __restrict__ Cptr,
                                               int N)
{
    __shared__ __align__(16) uint16_t sA[2][128 * 32];
    __shared__ __align__(16) uint16_t sB[2][128 * 32];

    const int t    = threadIdx.x;
    const int NB   = N >> 7;                       // N-tiles (9 or 3)
    const int bid  = blockIdx.x;
    const int chunk = bid / (8 * NB);
    const int r     = bid % (8 * NB);
    const int bm    = chunk * 8 + (r & 7);
    const int bn    = r >> 3;
    const int wave = t >> 6, lane = t & 63;
    const int wm   = (wave >> 1) * 64, wn = (wave & 1) * 64;
    const int lr   = lane & 15, quad = lane >> 4;

    const uint16_t* Ag = A  + (size_t)(bm * 128 + (t >> 2)) * GK + (t & 3) * 8;
    const uint16_t* Bg = Bt + (size_t)(bn * 128 + (t >> 2)) * GK + (t & 3) * 8;

    auto stage = [&](int buf, int k0) {
        g2l16(Ag + k0, sA[buf] + wave * 512);
        g2l16(Ag + (size_t)64 * GK + k0, sA[buf] + 2048 + wave * 512);
        g2l16(Bg + k0, sB[buf] + wave * 512);
        g2l16(Bg + (size_t)64 * GK + k0, sB[buf] + 2048 + wave * 512);
    };

    floatx4 acc[4][4] = {};

    stage(0, 0);
    __syncthreads();   // drain vmcnt(0): buf0 ready

    #pragma unroll
    for (int ks = 0; ks < 12; ++ks) {
        const int cur = ks & 1;
        if (ks < 11) stage(cur ^ 1, (ks + 1) * 32);   // prefetch next tile

        bf16x8 af[4], bfr[4];
        #pragma unroll
        for (int mt = 0; mt < 4; ++mt)
            af[mt] = *(const bf16x8*)&sA[cur][(wm + mt * 16 + lr) * 32 + quad * 8];
        #pragma unroll
        for (int nt = 0; nt < 4; ++nt)
            bfr[nt] = *(const bf16x8*)&sB[cur][(wn + nt * 16 + lr) * 32 + quad * 8];
        #pragma unroll
        for (int mt = 0; mt < 4; ++mt)
            #pragma unroll
            for (int nt = 0; nt < 4; ++nt)
                acc[mt][nt] = __builtin_amdgcn_mfma_f32_16x16x32_bf16(
                    af[mt], bfr[nt], acc[mt][nt], 0, 0, 0);

        __syncthreads();
    }

    // epilogue: C/D layout col=lane&15, row=quad*4+reg
    #pragma unroll
    for (int mt = 0; mt < 4; ++mt) {
        #pragma unroll
        for (int nt = 0; nt < 4; ++nt) {
            int gc = bn * 128 + wn + nt * 16 + lr;
            float bv = bias ? bias[gc] : 0.0f;
            int gr0 = bm * 128 + wm + mt * 16 + quad * 4;
            #pragma unroll
            for (int i = 0; i < 4; ++i) {
                if constexpr (CF32) {
                    ((float*)Cptr)[(size_t)(gr0 + i) * N + gc] = acc[mt][nt][i] + bv;
                } else {
                    ((uint16_t*)Cptr)[(size_t)(gr0 + i) * N + gc] = f2bf(acc[mt][nt][i] + bv);
                }
            }
        }
    }
}

// ---------------- MFMA windowed attention + fused depthwise conv ----------
// one wave per (b, window, head); 2 waves / 128-thread block; no barriers.
// LDS/wave: Pbuf 64x72 | Vt 32x72 (reused as convb after PV) | Vhalo 81x32
// plus warr: 288 conv weights + 32 bias (f32).
constexpr int PLD = 72;   // padded row stride (bf16 elems)
constexpr int WAVE_ELEMS = (64 + 32) * PLD + 81 * 32;   // 6912 + 2592

__global__ __launch_bounds__(128) void attn_mfma(const uint16_t* __restrict__ qkv,
                                                 const float* __restrict__ wconv,
                                                 const float* __restrict__ bconv,
                                                 uint16_t* __restrict__ y)
{
    __shared__ uint16_t lds[2][WAVE_ELEMS];
    __shared__ float    warr_all[2][320];

    const int wave = threadIdx.x >> 6;
    const int lane = threadIdx.x & 63;
    const int unit = blockIdx.x * 2 + wave;          // 0..12287
    const int h  = unit % HEADS;
    const int w  = (unit / HEADS) & 63;
    const int b  = unit / (HEADS * 64);
    const int wy = w >> 3, wx = w & 7;
    const int lr = lane & 15, quad = lane >> 4;

    uint16_t* Pbuf  = lds[wave];
    uint16_t* Vt    = lds[wave] + 64 * PLD;
    uint16_t* Vhalo = lds[wave] + 96 * PLD;          // [81][32]
    float*    warr  = warr_all[wave];                // [0,288) weights, [288,320) bias

    // ---- stage conv weights + bias ----
    #pragma unroll
    for (int it = 0; it < 5; ++it) {
        int idx = it * 64 + lane;
        if (idx < 288) warr[idx] = wconv[(idx >> 5) * DIMC + h * 32 + (idx & 31)];
    }
    if (lane < 32) warr[288 + lane] = bconv[h * 32 + lane];

    // ---- stage V halo: Vhalo[hy*9+hx][0..31], zero outside image ----
    #pragma unroll
    for (int it = 0; it < 6; ++it) {
        int u = it * 16 + (lane >> 2);               // halo token 0..95
        int g = lane & 3;
        if (u < 81) {
            int hy = u / 9, hx = u % 9;
            int iy = wy * 7 + hy - 1, ix = wx * 7 + hx - 1;
            uint4 val{0, 0, 0, 0};
            if (iy >= 0 && iy < IMH && ix >= 0 && ix < IMW)
                val = *(const uint4*)(qkv + (size_t)(b * NTOK + iy * IMW + ix) * QKVLD
                                      + 2 * DIMC + h * 32 + g * 8);
            *(uint4*)&Vhalo[u * 32 + g * 8] = val;
        }
    }

    auto rowbase = [&](int i, int which) -> const uint16_t* {
        int py = i / 7, px = i % 7;
        int n = (wy * 7 + py) * IMW + wx * 7 + px;
        return qkv + (size_t)(b * NTOK + n) * QKVLD + which * DIMC + h * 32;
    };

    uint4 qf[4], kf[4];
    #pragma unroll
    for (int tm = 0; tm < 4; ++tm) {
        int i = tm * 16 + lr;
        if (i < 49) {
            qf[tm] = *(const uint4*)(rowbase(i, 0) + quad * 8);
            kf[tm] = *(const uint4*)(rowbase(i, 1) + quad * 8);
        } else {
            qf[tm] = uint4{0, 0, 0, 0};
            kf[tm] = uint4{0, 0, 0, 0};
        }
    }

    {   // build Vt[d][j] (transposed window V) from Vhalo
        int j = lane;
        if (j < 49) {
            int hrow = (j / 7 + 1) * 9 + (j % 7 + 1);
            #pragma unroll
            for (int p = 0; p < 4; ++p) {
                U16x8 tmp; tmp.u = *(const uint4*)&Vhalo[hrow * 32 + p * 8];
                #pragma unroll
                for (int q = 0; q < 8; ++q) Vt[(p * 8 + q) * PLD + j] = tmp.h[q];
            }
        } else {
            #pragma unroll
            for (int d = 0; d < 32; ++d) Vt[d * PLD + j] = 0;
        }
    }

    floatx4 S[4][4] = {};
    #pragma unroll
    for (int tm = 0; tm < 4; ++tm)
        #pragma unroll
        for (int tn = 0; tn < 4; ++tn)
            S[tm][tn] = __builtin_amdgcn_mfma_f32_16x16x32_bf16(
                as_bf8(qf[tm]), as_bf8(kf[tn]), S[tm][tn], 0, 0, 0);

    const float scale = 0.17677669529663687f;  // 32^-0.5
    const bool v3 = (lr == 0);
    #pragma unroll
    for (int tm = 0; tm < 4; ++tm) {
        #pragma unroll
        for (int i = 0; i < 4; ++i) {
            float e0 = __expf(S[tm][0][i] * scale);
            float e1 = __expf(S[tm][1][i] * scale);
            float e2 = __expf(S[tm][2][i] * scale);
            float e3 = v3 ? __expf(S[tm][3][i] * scale) : 0.0f;
            float s = e0 + e1 + e2 + e3;
            #pragma unroll
            for (int d = 1; d < 16; d <<= 1) s += __shfl_xor(s, d);
            float inv = 1.0f / s;
            int row = tm * 16 + quad * 4 + i;
            Pbuf[row * PLD + lr]      = f2bf(e0 * inv);
            Pbuf[row * PLD + 16 + lr] = f2bf(e1 * inv);
            Pbuf[row * PLD + 32 + lr] = f2bf(e2 * inv);
            Pbuf[row * PLD + 48 + lr] = f2bf(e3 * inv);
        }
    }

    floatx4 O[4][2] = {};
    #pragma unroll
    for (int kk = 0; kk < 2; ++kk) {
        bf16x8 pf[4], vf[2];
        #pragma unroll
        for (int tm = 0; tm < 4; ++tm)
            pf[tm] = *(const bf16x8*)&Pbuf[(tm * 16 + lr) * PLD + kk * 32 + quad * 8];
        #pragma unroll
        for (int tn = 0; tn < 2; ++tn)
            vf[tn] = *(const bf16x8*)&Vt[(tn * 16 + lr) * PLD + kk * 32 + quad * 8];
        #pragma unroll
        for (int tm = 0; tm < 4; ++tm)
            #pragma unroll
            for (int tn = 0; tn < 2; ++tn)
                O[tm][tn] = __builtin_amdgcn_mfma_f32_16x16x32_bf16(
                    pf[tm], vf[tn], O[tm][tn], 0, 0, 0);
    }

    // ---- fused depthwise 3x3 conv: convb[j][c] over 49 tokens x 32 ch ----
    // Vt is dead after PV (same-wave DS ordering); reuse it as convb [49][32].
    uint16_t* convb = Vt;
    #pragma unroll
    for (int it = 0; it < 4; ++it) {
        int u = it * 64 + lane;                      // (token j, 8-ch group g)
        if (u < 196) {
            int j = u >> 2, g = u & 3;
            int py = j / 7, px = j % 7;
            float acc[8];
            {
                float4 b0 = *(const float4*)(warr + 288 + g * 8);
                float4 b1 = *(const float4*)(warr + 288 + g * 8 + 4);
                acc[0] = b0.x; acc[1] = b0.y; acc[2] = b0.z; acc[3] = b0.w;
                acc[4] = b1.x; acc[5] = b1.y; acc[6] = b1.z; acc[7] = b1.w;
            }
            #pragma unroll
            for (int ky = 0; ky < 3; ++ky) {
                #pragma unroll
                for (int kx = 0; kx < 3; ++kx) {
                    int hrow = (py + ky) * 9 + (px + kx);
                    U16x8 v; v.u = *(const uint4*)&Vhalo[hrow * 32 + g * 8];
                    const float* wp = warr + (ky * 3 + kx) * 32 + g * 8;
                    float4 w0 = *(const float4*)wp;
                    float4 w1 = *(const float4*)(wp + 4);
                    acc[0] += bf2f(v.h[0]) * w0.x;
                    acc[1] += bf2f(v.h[1]) * w0.y;
                    acc[2] += bf2f(v.h[2]) * w0.z;
                    acc[3] += bf2f(v.h[3]) * w0.w;
                    acc[4] += bf2f(v.h[4]) * w1.x;
                    acc[5] += bf2f(v.h[5]) * w1.y;
                    acc[6] += bf2f(v.h[6]) * w1.z;
                    acc[7] += bf2f(v.h[7]) * w1.w;
                }
            }
            U16x8 r;
            #pragma unroll
            for (int q = 0; q < 8; ++q) r.h[q] = f2bf(acc[q]);
            *(uint4*)&convb[j * 32 + g * 8] = r.u;
        }
    }

    // ---- epilogue: y = O + conv ----
    #pragma unroll
    for (int tm = 0; tm < 4; ++tm) {
        #pragma unroll
        for (int i = 0; i < 4; ++i) {
            int r = tm * 16 + quad * 4 + i;
            if (r < 49) {
                int py = r / 7, px = r % 7;
                int n = (wy * 7 + py) * IMW + wx * 7 + px;
                uint16_t* dst = y + (size_t)(b * NTOK + n) * DIMC + h * 32;
                float c0 = bf2f(convb[r * 32 + lr]);
                float c1 = bf2f(convb[r * 32 + 16 + lr]);
                dst[lr]      = f2bf(O[tm][0][i] + c0);
                dst[16 + lr] = f2bf(O[tm][1][i] + c1);
            }
        }
    }
}

// ---------------- launch ----------------
extern "C" void kernel_launch(void* const* d_in, const int* in_sizes, int n_in,
                              void* d_out, int out_size, void* d_ws, size_t ws_size,
                              hipStream_t stream)
{
    const float* x      = (const float*)d_in[0];
    const float* w_qkv  = (const float*)d_in[1];
    const float* w_proj = (const float*)d_in[2];
    const float* b_proj = (const float*)d_in[3];
    const float* w_conv = (const float*)d_in[4];
    const float* b_conv = (const float*)d_in[5];
    float* out = (float*)d_out;

    // ws layout (155.3 MB):
    //  [0, 115605504)              qkv bf16 (50176 x 1152)
    //  [115605504, +38535168)      xb bf16 (50176 x 384), reused as y bf16 after GEMM1
    //  then wqkvT bf16 (1152x384), wprojT bf16 (384x384)
    char* ws = (char*)d_ws;
    uint16_t* qkv    = (uint16_t*)ws;
    uint16_t* xb     = (uint16_t*)(ws + 115605504);
    uint16_t* yb     = xb;  // alias: xb dead after GEMM1
    uint16_t* wqkvT  = (uint16_t*)(ws + 115605504 + 38535168);
    uint16_t* wprojT = wqkvT + QKVLD * GK;

    // prep
    cvt_bf16<<<dim3((MTOT * DIMC) / (8 * 256)), 256, 0, stream>>>(x, xb);
    transpose_cvt<<<dim3((GK * QKVLD) / 256), 256, 0, stream>>>(w_qkv, wqkvT, GK, QKVLD);
    transpose_cvt<<<dim3((GK * DIMC) / 256), 256, 0, stream>>>(w_proj, wprojT, GK, DIMC);

    // 1) qkv = xb @ w_qkv   (M=50176, N=1152), bf16 out  [1D grid, supertiled]
    gemm_bt<false><<<dim3((MTOT / 128) * (QKVLD / 128)), 256, 0, stream>>>(
        xb, wqkvT, nullptr, qkv, QKVLD);

    // 2) MFMA windowed attention + fused depthwise conv -> y (bf16)
    attn_mfma<<<dim3(BATCH * 64 * HEADS / 2), 128, 0, stream>>>(
        qkv, w_conv, b_conv, yb);

    // 3) out = y @ w_proj + b_proj (M=50176, N=384), fp32 out  [1D grid]
    gemm_bt<true><<<dim3((MTOT / 128) * (DIMC / 128)), 256, 0, stream>>>(
        yb, wprojT, b_proj, out, DIMC);
}

// Round 5
// 307.513 us; speedup vs baseline: 1.5092x; 1.0412x over previous
//
#include <hip/hip_runtime.h>
#include <cstdint>
#include <cstddef>

typedef __bf16 bf16x8 __attribute__((ext_vector_type(8)));
typedef float floatx4 __attribute__((ext_vector_type(4)));

#define DEV static __device__ __forceinline__

DEV float bf2f(uint16_t u) {
    union { uint32_t i; float f; } x; x.i = ((uint32_t)u) << 16; return x.f;
}
DEV uint16_t f2bf(float f) {
    uint32_t u = __float_as_uint(f);
    uint32_t r = (u + 0x7FFFu + ((u >> 16) & 1u)) >> 16;   // RNE
    return (uint16_t)r;
}
DEV bf16x8 as_bf8(uint4 u) {
    union { uint4 u; bf16x8 b; } c; c.u = u; return c.b;
}
// async global->LDS, 16B per lane. LDS dest must be wave-uniform base (+lane*16 by HW).
DEV void g2l16(const void* g, void* l) {
    __builtin_amdgcn_global_load_lds(
        (const __attribute__((address_space(1))) void*)g,
        (__attribute__((address_space(3))) void*)l, 16, 0, 0);
}

union U16x8 { uint16_t h[8]; uint4 u; };

// ---------------- problem constants ----------------
constexpr int DIMC  = 384;
constexpr int HEADS = 12;
constexpr int IMH   = 56, IMW = 56;
constexpr int NTOK  = IMH * IMW;        // 3136
constexpr int BATCH = 16;
constexpr int MTOT  = BATCH * NTOK;     // 50176
constexpr int QKVLD = 3 * DIMC;         // 1152
constexpr int GK    = 384;              // K for both GEMMs

// ---------------- prep: fp32 -> bf16 (8 elems/thread) ----------------
__global__ __launch_bounds__(256) void cvt_bf16(const float* __restrict__ in,
                                                uint16_t* __restrict__ out)
{
    size_t i = ((size_t)blockIdx.x * 256 + threadIdx.x) * 8;
    float4 a = *(const float4*)(in + i);
    float4 b = *(const float4*)(in + i + 4);
    U16x8 t;
    t.h[0] = f2bf(a.x); t.h[1] = f2bf(a.y); t.h[2] = f2bf(a.z); t.h[3] = f2bf(a.w);
    t.h[4] = f2bf(b.x); t.h[5] = f2bf(b.y); t.h[6] = f2bf(b.z); t.h[7] = f2bf(b.w);
    *(uint4*)(out + i) = t.u;
}

// ---------------- prep: in[R][C] fp32 -> out[C][R] bf16 ----------------
__global__ __launch_bounds__(256) void transpose_cvt(const float* __restrict__ in,
                                                     uint16_t* __restrict__ out,
                                                     int R, int C)
{
    int idx = blockIdx.x * 256 + threadIdx.x;   // output-linear: idx = c*R + r
    int r = idx % R, c = idx / R;
    out[idx] = f2bf(in[(size_t)r * C + c]);
}

// ---------------- GEMM: C[M,N] = A[M,K=384] @ Bt[N,K]^T ----
// 2-phase double-buffered pipeline; 1D grid with M-supertile-8 XCD swizzle.
template<bool CF32>
__global__ __launch_bounds__(256) void gemm_bt(const uint16_t* __restrict__ A,
                                               const uint16_t* __restrict__ Bt,
                                               const float* __restrict__ bias,
                                               void* __restrict__ Cptr,
                                               int N)
{
    __shared__ __align__(16) uint16_t sA[2][128 * 32];
    __shared__ __align__(16) uint16_t sB[2][128 * 32];

    const int t    = threadIdx.x;
    const int NB   = N >> 7;                       // N-tiles (9 or 3)
    const int bid  = blockIdx.x;
    const int chunk = bid / (8 * NB);
    const int r     = bid % (8 * NB);
    const int bm    = chunk * 8 + (r & 7);
    const int bn    = r >> 3;
    const int wave = t >> 6, lane = t & 63;
    const int wm   = (wave >> 1) * 64, wn = (wave & 1) * 64;
    const int lr   = lane & 15, quad = lane >> 4;

    const uint16_t* Ag = A  + (size_t)(bm * 128 + (t >> 2)) * GK + (t & 3) * 8;
    const uint16_t* Bg = Bt + (size_t)(bn * 128 + (t >> 2)) * GK + (t & 3) * 8;

    auto stage = [&](int buf, int k0) {
        g2l16(Ag + k0, sA[buf] + wave * 512);
        g2l16(Ag + (size_t)64 * GK + k0, sA[buf] + 2048 + wave * 512);
        g2l16(Bg + k0, sB[buf] + wave * 512);
        g2l16(Bg + (size_t)64 * GK + k0, sB[buf] + 2048 + wave * 512);
    };

    floatx4 acc[4][4] = {};

    stage(0, 0);
    __syncthreads();   // drain vmcnt(0): buf0 ready

    #pragma unroll
    for (int ks = 0; ks < 12; ++ks) {
        const int cur = ks & 1;
        if (ks < 11) stage(cur ^ 1, (ks + 1) * 32);   // prefetch next tile

        bf16x8 af[4], bfr[4];
        #pragma unroll
        for (int mt = 0; mt < 4; ++mt)
            af[mt] = *(const bf16x8*)&sA[cur][(wm + mt * 16 + lr) * 32 + quad * 8];
        #pragma unroll
        for (int nt = 0; nt < 4; ++nt)
            bfr[nt] = *(const bf16x8*)&sB[cur][(wn + nt * 16 + lr) * 32 + quad * 8];
        #pragma unroll
        for (int mt = 0; mt < 4; ++mt)
            #pragma unroll
            for (int nt = 0; nt < 4; ++nt)
                acc[mt][nt] = __builtin_amdgcn_mfma_f32_16x16x32_bf16(
                    af[mt], bfr[nt], acc[mt][nt], 0, 0, 0);

        __syncthreads();
    }

    // epilogue: C/D layout col=lane&15, row=quad*4+reg
    #pragma unroll
    for (int mt = 0; mt < 4; ++mt) {
        #pragma unroll
        for (int nt = 0; nt < 4; ++nt) {
            int gc = bn * 128 + wn + nt * 16 + lr;
            float bv = bias ? bias[gc] : 0.0f;
            int gr0 = bm * 128 + wm + mt * 16 + quad * 4;
            #pragma unroll
            for (int i = 0; i < 4; ++i) {
                if constexpr (CF32) {
                    ((float*)Cptr)[(size_t)(gr0 + i) * N + gc] = acc[mt][nt][i] + bv;
                } else {
                    ((uint16_t*)Cptr)[(size_t)(gr0 + i) * N + gc] = f2bf(acc[mt][nt][i] + bv);
                }
            }
        }
    }
}

// ---------------- MFMA windowed attention + fused depthwise conv ----------
// one wave per (b, window, head); 2 waves / 128-thread block; no barriers.
// Swapped-operand scheme: S^T = mfma(K,Q) so softmax k-dim is register-local
// (2 shfl_xor per q-tile); P^T stays in registers (cvt_pk bf16 pairs) and PV
// B-fragments are built via lane shuffles -> NO Pbuf in LDS.
// LDS/wave: Vt 32x72 (reused as convb after PV) | Vhalo 81x32 | warr 320 f32.
constexpr int PLD = 72;   // padded row stride (bf16 elems)
constexpr int WAVE_ELEMS = 32 * PLD + 81 * 32;   // 2304 + 2592 = 4896

__global__ __launch_bounds__(128) void attn_mfma(const uint16_t* __restrict__ qkv,
                                                 const float* __restrict__ wconv,
                                                 const float* __restrict__ bconv,
                                                 uint16_t* __restrict__ y)
{
    __shared__ uint16_t lds[2][WAVE_ELEMS];
    __shared__ float    warr_all[2][320];

    const int wave = threadIdx.x >> 6;
    const int lane = threadIdx.x & 63;
    const int unit = blockIdx.x * 2 + wave;          // 0..12287
    const int h  = unit % HEADS;
    const int w  = (unit / HEADS) & 63;
    const int b  = unit / (HEADS * 64);
    const int wy = w >> 3, wx = w & 7;
    const int lr = lane & 15, quad = lane >> 4;

    uint16_t* Vt    = lds[wave];                     // [32][PLD]
    uint16_t* Vhalo = lds[wave] + 32 * PLD;          // [81][32]
    float*    warr  = warr_all[wave];                // [0,288) weights, [288,320) bias

    // ---- stage conv weights + bias ----
    #pragma unroll
    for (int it = 0; it < 5; ++it) {
        int idx = it * 64 + lane;
        if (idx < 288) warr[idx] = wconv[(idx >> 5) * DIMC + h * 32 + (idx & 31)];
    }
    if (lane < 32) warr[288 + lane] = bconv[h * 32 + lane];

    // ---- stage V halo: Vhalo[hy*9+hx][0..31], zero outside image ----
    #pragma unroll
    for (int it = 0; it < 6; ++it) {
        int u = it * 16 + (lane >> 2);               // halo token 0..95
        int g = lane & 3;
        if (u < 81) {
            int hy = u / 9, hx = u % 9;
            int iy = wy * 7 + hy - 1, ix = wx * 7 + hx - 1;
            uint4 val{0, 0, 0, 0};
            if (iy >= 0 && iy < IMH && ix >= 0 && ix < IMW)
                val = *(const uint4*)(qkv + (size_t)(b * NTOK + iy * IMW + ix) * QKVLD
                                      + 2 * DIMC + h * 32 + g * 8);
            *(uint4*)&Vhalo[u * 32 + g * 8] = val;
        }
    }

    auto rowbase = [&](int i, int which) -> const uint16_t* {
        int py = i / 7, px = i % 7;
        int n = (wy * 7 + py) * IMW + wx * 7 + px;
        return qkv + (size_t)(b * NTOK + n) * QKVLD + which * DIMC + h * 32;
    };

    uint4 qf[4], kf[4];
    #pragma unroll
    for (int tm = 0; tm < 4; ++tm) {
        int i = tm * 16 + lr;
        if (i < 49) {
            qf[tm] = *(const uint4*)(rowbase(i, 0) + quad * 8);
            kf[tm] = *(const uint4*)(rowbase(i, 1) + quad * 8);
        } else {
            qf[tm] = uint4{0, 0, 0, 0};
            kf[tm] = uint4{0, 0, 0, 0};
        }
    }

    {   // build Vt[d][j] (transposed window V) from Vhalo
        int j = lane;
        if (j < 49) {
            int hrow = (j / 7 + 1) * 9 + (j % 7 + 1);
            #pragma unroll
            for (int p = 0; p < 4; ++p) {
                U16x8 tmp; tmp.u = *(const uint4*)&Vhalo[hrow * 32 + p * 8];
                #pragma unroll
                for (int q = 0; q < 8; ++q) Vt[(p * 8 + q) * PLD + j] = tmp.h[q];
            }
        } else {
            #pragma unroll
            for (int d = 0; d < 32; ++d) Vt[d * PLD + j] = 0;
        }
    }

    // ---- S^T[k][q] = mfma(K, Q): row k = ta*16+quad*4+i, col q = tb*16+lr
    floatx4 S[4][4] = {};
    #pragma unroll
    for (int ta = 0; ta < 4; ++ta)
        #pragma unroll
        for (int tb = 0; tb < 4; ++tb)
            S[ta][tb] = __builtin_amdgcn_mfma_f32_16x16x32_bf16(
                as_bf8(kf[ta]), as_bf8(qf[tb]), S[ta][tb], 0, 0, 0);

    // ---- softmax over k (register-local 16 values + cross-quad reduce) ----
    const float scale = 0.17677669529663687f;  // 32^-0.5
    float psum[4] = {0.f, 0.f, 0.f, 0.f};
    #pragma unroll
    for (int ta = 0; ta < 4; ++ta) {
        #pragma unroll
        for (int tb = 0; tb < 4; ++tb) {
            #pragma unroll
            for (int i = 0; i < 4; ++i) {
                float e;
                if (ta < 3) e = __expf(S[ta][tb][i] * scale);
                else        e = (quad == 0 && i == 0)
                                ? __expf(S[ta][tb][i] * scale) : 0.0f;  // k=48 only
                S[ta][tb][i] = e;
                psum[tb] += e;
            }
        }
    }
    #pragma unroll
    for (int tb = 0; tb < 4; ++tb) {
        float s = psum[tb];
        s += __shfl_xor(s, 16);
        s += __shfl_xor(s, 32);
        psum[tb] = 1.0f / s;
    }

    // pack P^T to bf16 pairs: pkv[ta][tb][hh] = (P[2hh], P[2hh+1])
    uint32_t pkv[4][4][2];
    #pragma unroll
    for (int ta = 0; ta < 4; ++ta) {
        #pragma unroll
        for (int tb = 0; tb < 4; ++tb) {
            #pragma unroll
            for (int hh = 0; hh < 2; ++hh) {
                float lo = S[ta][tb][2 * hh]     * psum[tb];
                float hi = S[ta][tb][2 * hh + 1] * psum[tb];
                asm("v_cvt_pk_bf16_f32 %0, %1, %2"
                    : "=v"(pkv[ta][tb][hh]) : "v"(lo), "v"(hi));
            }
        }
    }

    // ---- PV: O^T[d][q] = mfma(V^T_frag, P^T_frag) ----
    // B-frag (tb,kk) elem e: j = kk*32+quad*8+e, from lane (quad&1)*32+lr (+16
    // for e>=4), array pkv[kk*2 + (quad>=2)][tb][(e&3)>>1 pair].
    const int lo_lane = (quad & 1) * 32 + lr;
    const bool hiq = quad >= 2;
    floatx4 Ot[2][4] = {};
    #pragma unroll
    for (int kk = 0; kk < 2; ++kk) {
        uint4 pfr[4];
        #pragma unroll
        for (int tb = 0; tb < 4; ++tb) {
            uint32_t a0 = (uint32_t)__shfl((int)pkv[kk * 2][tb][0],     lo_lane);
            uint32_t b0 = (uint32_t)__shfl((int)pkv[kk * 2 + 1][tb][0], lo_lane);
            uint32_t a1 = (uint32_t)__shfl((int)pkv[kk * 2][tb][1],     lo_lane);
            uint32_t b1 = (uint32_t)__shfl((int)pkv[kk * 2 + 1][tb][1], lo_lane);
            uint32_t a2 = (uint32_t)__shfl((int)pkv[kk * 2][tb][0],     lo_lane + 16);
            uint32_t b2 = (uint32_t)__shfl((int)pkv[kk * 2 + 1][tb][0], lo_lane + 16);
            uint32_t a3 = (uint32_t)__shfl((int)pkv[kk * 2][tb][1],     lo_lane + 16);
            uint32_t b3 = (uint32_t)__shfl((int)pkv[kk * 2 + 1][tb][1], lo_lane + 16);
            pfr[tb] = uint4{hiq ? b0 : a0, hiq ? b1 : a1,
                            hiq ? b2 : a2, hiq ? b3 : a3};
        }
        bf16x8 vf[2];
        #pragma unroll
        for (int td = 0; td < 2; ++td)
            vf[td] = *(const bf16x8*)&Vt[(td * 16 + lr) * PLD + kk * 32 + quad * 8];
        #pragma unroll
        for (int td = 0; td < 2; ++td)
            #pragma unroll
            for (int tb = 0; tb < 4; ++tb)
                Ot[td][tb] = __builtin_amdgcn_mfma_f32_16x16x32_bf16(
                    vf[td], as_bf8(pfr[tb]), Ot[td][tb], 0, 0, 0);
    }

    // ---- fused depthwise 3x3 conv: convb[j][c] over 49 tokens x 32 ch ----
    // Vt is dead after PV (same-wave DS ordering); reuse it as convb [49][32].
    uint16_t* convb = Vt;
    #pragma unroll
    for (int it = 0; it < 4; ++it) {
        int u = it * 64 + lane;                      // (token j, 8-ch group g)
        if (u < 196) {
            int j = u >> 2, g = u & 3;
            int py = j / 7, px = j % 7;
            float acc[8];
            {
                float4 b0 = *(const float4*)(warr + 288 + g * 8);
                float4 b1 = *(const float4*)(warr + 288 + g * 8 + 4);
                acc[0] = b0.x; acc[1] = b0.y; acc[2] = b0.z; acc[3] = b0.w;
                acc[4] = b1.x; acc[5] = b1.y; acc[6] = b1.z; acc[7] = b1.w;
            }
            #pragma unroll
            for (int ky = 0; ky < 3; ++ky) {
                #pragma unroll
                for (int kx = 0; kx < 3; ++kx) {
                    int hrow = (py + ky) * 9 + (px + kx);
                    U16x8 v; v.u = *(const uint4*)&Vhalo[hrow * 32 + g * 8];
                    const float* wp = warr + (ky * 3 + kx) * 32 + g * 8;
                    float4 w0 = *(const float4*)wp;
                    float4 w1 = *(const float4*)(wp + 4);
                    acc[0] += bf2f(v.h[0]) * w0.x;
                    acc[1] += bf2f(v.h[1]) * w0.y;
                    acc[2] += bf2f(v.h[2]) * w0.z;
                    acc[3] += bf2f(v.h[3]) * w0.w;
                    acc[4] += bf2f(v.h[4]) * w1.x;
                    acc[5] += bf2f(v.h[5]) * w1.y;
                    acc[6] += bf2f(v.h[6]) * w1.z;
                    acc[7] += bf2f(v.h[7]) * w1.w;
                }
            }
            U16x8 rr;
            #pragma unroll
            for (int q = 0; q < 8; ++q) rr.h[q] = f2bf(acc[q]);
            *(uint4*)&convb[j * 32 + g * 8] = rr.u;
        }
    }

    // ---- epilogue: y[q][d] = Ot[td][tb][i] + conv; q=tb*16+lr, d=td*16+quad*4+i
    #pragma unroll
    for (int tb = 0; tb < 4; ++tb) {
        int q = tb * 16 + lr;
        if (q < 49) {
            int py = q / 7, px = q % 7;
            int n = (wy * 7 + py) * IMW + wx * 7 + px;
            uint16_t* dst = y + (size_t)(b * NTOK + n) * DIMC + h * 32;
            #pragma unroll
            for (int td = 0; td < 2; ++td) {
                int d0 = td * 16 + quad * 4;
                uint2 cv = *(const uint2*)&convb[q * 32 + d0];
                float o0 = Ot[td][tb][0] + bf2f((uint16_t)(cv.x & 0xffffu));
                float o1 = Ot[td][tb][1] + bf2f((uint16_t)(cv.x >> 16));
                float o2 = Ot[td][tb][2] + bf2f((uint16_t)(cv.y & 0xffffu));
                float o3 = Ot[td][tb][3] + bf2f((uint16_t)(cv.y >> 16));
                uint32_t w0, w1;
                asm("v_cvt_pk_bf16_f32 %0, %1, %2" : "=v"(w0) : "v"(o0), "v"(o1));
                asm("v_cvt_pk_bf16_f32 %0, %1, %2" : "=v"(w1) : "v"(o2), "v"(o3));
                *(uint2*)(dst + d0) = uint2{w0, w1};
            }
        }
    }
}

// ---------------- launch ----------------
extern "C" void kernel_launch(void* const* d_in, const int* in_sizes, int n_in,
                              void* d_out, int out_size, void* d_ws, size_t ws_size,
                              hipStream_t stream)
{
    const float* x      = (const float*)d_in[0];
    const float* w_qkv  = (const float*)d_in[1];
    const float* w_proj = (const float*)d_in[2];
    const float* b_proj = (const float*)d_in[3];
    const float* w_conv = (const float*)d_in[4];
    const float* b_conv = (const float*)d_in[5];
    float* out = (float*)d_out;

    // ws layout (155.3 MB):
    //  [0, 115605504)              qkv bf16 (50176 x 1152)
    //  [115605504, +38535168)      xb bf16 (50176 x 384), reused as y bf16 after GEMM1
    //  then wqkvT bf16 (1152x384), wprojT bf16 (384x384)
    char* ws = (char*)d_ws;
    uint16_t* qkv    = (uint16_t*)ws;
    uint16_t* xb     = (uint16_t*)(ws + 115605504);
    uint16_t* yb     = xb;  // alias: xb dead after GEMM1
    uint16_t* wqkvT  = (uint16_t*)(ws + 115605504 + 38535168);
    uint16_t* wprojT = wqkvT + QKVLD * GK;

    // prep
    cvt_bf16<<<dim3((MTOT * DIMC) / (8 * 256)), 256, 0, stream>>>(x, xb);
    transpose_cvt<<<dim3((GK * QKVLD) / 256), 256, 0, stream>>>(w_qkv, wqkvT, GK, QKVLD);
    transpose_cvt<<<dim3((GK * DIMC) / 256), 256, 0, stream>>>(w_proj, wprojT, GK, DIMC);

    // 1) qkv = xb @ w_qkv   (M=50176, N=1152), bf16 out  [1D grid, supertiled]
    gemm_bt<false><<<dim3((MTOT / 128) * (QKVLD / 128)), 256, 0, stream>>>(
        xb, wqkvT, nullptr, qkv, QKVLD);

    // 2) MFMA windowed attention + fused depthwise conv -> y (bf16)
    attn_mfma<<<dim3(BATCH * 64 * HEADS / 2), 128, 0, stream>>>(
        qkv, w_conv, b_conv, yb);

    // 3) out = y @ w_proj + b_proj (M=50176, N=384), fp32 out  [1D grid]
    gemm_bt<true><<<dim3((MTOT / 128) * (DIMC / 128)), 256, 0, stream>>>(
        yb, wprojT, b_proj, out, DIMC);
}

// Round 6
// 300.890 us; speedup vs baseline: 1.5424x; 1.0220x over previous
//
#include <hip/hip_runtime.h>
#include <cstdint>
#include <cstddef>

typedef __bf16 bf16x8 __attribute__((ext_vector_type(8)));
typedef float floatx4 __attribute__((ext_vector_type(4)));

#define DEV static __device__ __forceinline__

DEV float bf2f(uint16_t u) {
    union { uint32_t i; float f; } x; x.i = ((uint32_t)u) << 16; return x.f;
}
DEV uint16_t f2bf(float f) {
    uint32_t u = __float_as_uint(f);
    uint32_t r = (u + 0x7FFFu + ((u >> 16) & 1u)) >> 16;   // RNE
    return (uint16_t)r;
}
DEV bf16x8 as_bf8(uint4 u) {
    union { uint4 u; bf16x8 b; } c; c.u = u; return c.b;
}
// async global->LDS, 16B per lane. LDS dest must be wave-uniform base (+lane*16 by HW).
DEV void g2l16(const void* g, void* l) {
    __builtin_amdgcn_global_load_lds(
        (const __attribute__((address_space(1))) void*)g,
        (__attribute__((address_space(3))) void*)l, 16, 0, 0);
}

union U16x8 { uint16_t h[8]; uint4 u; };

// ---------------- problem constants ----------------
constexpr int DIMC  = 384;
constexpr int HEADS = 12;
constexpr int IMH   = 56, IMW = 56;
constexpr int NTOK  = IMH * IMW;        // 3136
constexpr int BATCH = 16;
constexpr int MTOT  = BATCH * NTOK;     // 50176
constexpr int QKVLD = 3 * DIMC;         // 1152
constexpr int GK    = 384;              // K for both GEMMs
constexpr int MTILES_PAD = 200;         // 196 real 256-row tiles, padded to %8==0

// ---------------- fused prep: cvt x -> bf16, transpose both weights -------
constexpr int CVTB  = (MTOT * DIMC) / (8 * 256);     // 9408
constexpr int TQKVB = (GK * QKVLD) / 256;            // 1728
constexpr int TPRJB = (GK * DIMC) / 256;             // 576

__global__ __launch_bounds__(256) void prep_kernel(
    const float* __restrict__ x,      uint16_t* __restrict__ xb,
    const float* __restrict__ w_qkv,  uint16_t* __restrict__ wqkvT,
    const float* __restrict__ w_proj, uint16_t* __restrict__ wprojT)
{
    int bid = blockIdx.x;
    int t   = threadIdx.x;
    if (bid < CVTB) {
        size_t i = ((size_t)bid * 256 + t) * 8;
        float4 a = *(const float4*)(x + i);
        float4 b = *(const float4*)(x + i + 4);
        U16x8 o;
        o.h[0] = f2bf(a.x); o.h[1] = f2bf(a.y); o.h[2] = f2bf(a.z); o.h[3] = f2bf(a.w);
        o.h[4] = f2bf(b.x); o.h[5] = f2bf(b.y); o.h[6] = f2bf(b.z); o.h[7] = f2bf(b.w);
        *(uint4*)(xb + i) = o.u;
    } else if (bid < CVTB + TQKVB) {
        int idx = (bid - CVTB) * 256 + t;            // idx = c*GK + r
        int r = idx % GK, c = idx / GK;
        wqkvT[idx] = f2bf(w_qkv[(size_t)r * QKVLD + c]);
    } else {
        int idx = (bid - CVTB - TQKVB) * 256 + t;
        int r = idx % GK, c = idx / GK;
        wprojT[idx] = f2bf(w_proj[(size_t)r * DIMC + c]);
    }
}

// ---------------- GEMM: C[M,N] = A[M,K=384] @ Bt[N,K]^T ----
// 256x128 tile, 8 waves (512 thr), 2-phase double-buffered (same sync skeleton
// as the verified 128^2 version -- parameter change only). 1D grid with
// M-supertile-8 XCD swizzle (MTILES padded to 200 for bijectivity; padded
// blocks stage garbage safely inside ws and skip their stores).
template<bool CF32>
__global__ __launch_bounds__(512) void gemm_bt(const uint16_t* __restrict__ A,
                                               const uint16_t* __restrict__ Bt,
                                               const float* __restrict__ bias,
                                               void* __restrict__ Cptr,
                                               int N)
{
    __shared__ __align__(16) uint16_t sA[2][256 * 32];   // 32 KB
    __shared__ __align__(16) uint16_t sB[2][128 * 32];   // 16 KB

    const int t    = threadIdx.x;
    const int NB   = N >> 7;                       // N-tiles (9 or 3)
    const int bid  = blockIdx.x;
    const int chunk = bid / (8 * NB);
    const int r     = bid % (8 * NB);
    const int bm    = chunk * 8 + (r & 7);         // 0..199
    const int bn    = r >> 3;
    const int wave = t >> 6, lane = t & 63;
    const int wm   = (wave >> 1) * 64;             // 0,64,128,192
    const int wn   = (wave & 1) * 64;              // 0,64
    const int lr   = lane & 15, quad = lane >> 4;
    const bool mvalid = (bm * 256 + 256) <= MTOT;  // padded tiles: compute, no store

    // staging: 512 thr x 16B = 8KB/call. A tile 16KB -> 2 calls, B tile 8KB -> 1.
    const uint16_t* Ag = A  + (size_t)(bm * 256 + (t >> 2)) * GK + (t & 3) * 8;
    const uint16_t* Bg = Bt + (size_t)(bn * 128 + (t >> 2)) * GK + (t & 3) * 8;

    auto stage = [&](int buf, int k0) {
        g2l16(Ag + k0, sA[buf] + wave * 512);                         // rows 0-127
        g2l16(Ag + (size_t)128 * GK + k0, sA[buf] + 4096 + wave * 512); // rows 128-255
        g2l16(Bg + k0, sB[buf] + wave * 512);                         // rows 0-127
    };

    floatx4 acc[4][4] = {};

    stage(0, 0);
    __syncthreads();   // drain vmcnt(0): buf0 ready

    #pragma unroll
    for (int ks = 0; ks < 12; ++ks) {
        const int cur = ks & 1;
        if (ks < 11) stage(cur ^ 1, (ks + 1) * 32);   // prefetch next tile

        bf16x8 af[4], bfr[4];
        #pragma unroll
        for (int mt = 0; mt < 4; ++mt)
            af[mt] = *(const bf16x8*)&sA[cur][(wm + mt * 16 + lr) * 32 + quad * 8];
        #pragma unroll
        for (int nt = 0; nt < 4; ++nt)
            bfr[nt] = *(const bf16x8*)&sB[cur][(wn + nt * 16 + lr) * 32 + quad * 8];
        #pragma unroll
        for (int mt = 0; mt < 4; ++mt)
            #pragma unroll
            for (int nt = 0; nt < 4; ++nt)
                acc[mt][nt] = __builtin_amdgcn_mfma_f32_16x16x32_bf16(
                    af[mt], bfr[nt], acc[mt][nt], 0, 0, 0);

        __syncthreads();
    }

    if (!mvalid) return;

    // epilogue: C/D layout col=lane&15, row=quad*4+reg
    #pragma unroll
    for (int mt = 0; mt < 4; ++mt) {
        #pragma unroll
        for (int nt = 0; nt < 4; ++nt) {
            int gc = bn * 128 + wn + nt * 16 + lr;
            float bv = bias ? bias[gc] : 0.0f;
            int gr0 = bm * 256 + wm + mt * 16 + quad * 4;
            #pragma unroll
            for (int i = 0; i < 4; ++i) {
                if constexpr (CF32) {
                    ((float*)Cptr)[(size_t)(gr0 + i) * N + gc] = acc[mt][nt][i] + bv;
                } else {
                    ((uint16_t*)Cptr)[(size_t)(gr0 + i) * N + gc] = f2bf(acc[mt][nt][i] + bv);
                }
            }
        }
    }
}

// ---------------- MFMA windowed attention + fused depthwise conv ----------
// one wave per (b, window, head); 2 waves / 128-thread block; no barriers.
// Swapped-operand scheme: S^T = mfma(K,Q) so softmax k-dim is register-local
// (2 shfl_xor per q-tile); P^T stays in registers (cvt_pk bf16 pairs) and PV
// B-fragments are built via lane shuffles -> NO Pbuf in LDS.
// LDS/wave: Vt 32x72 (reused as convb after PV) | Vhalo 81x32 | warr 320 f32.
constexpr int PLD = 72;   // padded row stride (bf16 elems)
constexpr int WAVE_ELEMS = 32 * PLD + 81 * 32;   // 2304 + 2592 = 4896

__global__ __launch_bounds__(128) void attn_mfma(const uint16_t* __restrict__ qkv,
                                                 const float* __restrict__ wconv,
                                                 const float* __restrict__ bconv,
                                                 uint16_t* __restrict__ y)
{
    __shared__ uint16_t lds[2][WAVE_ELEMS];
    __shared__ float    warr_all[2][320];

    const int wave = threadIdx.x >> 6;
    const int lane = threadIdx.x & 63;
    const int unit = blockIdx.x * 2 + wave;          // 0..12287
    const int h  = unit % HEADS;
    const int w  = (unit / HEADS) & 63;
    const int b  = unit / (HEADS * 64);
    const int wy = w >> 3, wx = w & 7;
    const int lr = lane & 15, quad = lane >> 4;

    uint16_t* Vt    = lds[wave];                     // [32][PLD]
    uint16_t* Vhalo = lds[wave] + 32 * PLD;          // [81][32]
    float*    warr  = warr_all[wave];                // [0,288) weights, [288,320) bias

    // ---- stage conv weights + bias ----
    #pragma unroll
    for (int it = 0; it < 5; ++it) {
        int idx = it * 64 + lane;
        if (idx < 288) warr[idx] = wconv[(idx >> 5) * DIMC + h * 32 + (idx & 31)];
    }
    if (lane < 32) warr[288 + lane] = bconv[h * 32 + lane];

    // ---- stage V halo: Vhalo[hy*9+hx][0..31], zero outside image ----
    #pragma unroll
    for (int it = 0; it < 6; ++it) {
        int u = it * 16 + (lane >> 2);               // halo token 0..95
        int g = lane & 3;
        if (u < 81) {
            int hy = u / 9, hx = u % 9;
            int iy = wy * 7 + hy - 1, ix = wx * 7 + hx - 1;
            uint4 val{0, 0, 0, 0};
            if (iy >= 0 && iy < IMH && ix >= 0 && ix < IMW)
                val = *(const uint4*)(qkv + (size_t)(b * NTOK + iy * IMW + ix) * QKVLD
                                      + 2 * DIMC + h * 32 + g * 8);
            *(uint4*)&Vhalo[u * 32 + g * 8] = val;
        }
    }

    auto rowbase = [&](int i, int which) -> const uint16_t* {
        int py = i / 7, px = i % 7;
        int n = (wy * 7 + py) * IMW + wx * 7 + px;
        return qkv + (size_t)(b * NTOK + n) * QKVLD + which * DIMC + h * 32;
    };

    uint4 qf[4], kf[4];
    #pragma unroll
    for (int tm = 0; tm < 4; ++tm) {
        int i = tm * 16 + lr;
        if (i < 49) {
            qf[tm] = *(const uint4*)(rowbase(i, 0) + quad * 8);
            kf[tm] = *(const uint4*)(rowbase(i, 1) + quad * 8);
        } else {
            qf[tm] = uint4{0, 0, 0, 0};
            kf[tm] = uint4{0, 0, 0, 0};
        }
    }

    {   // build Vt[d][j] (transposed window V) from Vhalo
        int j = lane;
        if (j < 49) {
            int hrow = (j / 7 + 1) * 9 + (j % 7 + 1);
            #pragma unroll
            for (int p = 0; p < 4; ++p) {
                U16x8 tmp; tmp.u = *(const uint4*)&Vhalo[hrow * 32 + p * 8];
                #pragma unroll
                for (int q = 0; q < 8; ++q) Vt[(p * 8 + q) * PLD + j] = tmp.h[q];
            }
        } else {
            #pragma unroll
            for (int d = 0; d < 32; ++d) Vt[d * PLD + j] = 0;
        }
    }

    // ---- S^T[k][q] = mfma(K, Q): row k = ta*16+quad*4+i, col q = tb*16+lr
    floatx4 S[4][4] = {};
    #pragma unroll
    for (int ta = 0; ta < 4; ++ta)
        #pragma unroll
        for (int tb = 0; tb < 4; ++tb)
            S[ta][tb] = __builtin_amdgcn_mfma_f32_16x16x32_bf16(
                as_bf8(kf[ta]), as_bf8(qf[tb]), S[ta][tb], 0, 0, 0);

    // ---- softmax over k (register-local 16 values + cross-quad reduce) ----
    const float scale = 0.17677669529663687f;  // 32^-0.5
    float psum[4] = {0.f, 0.f, 0.f, 0.f};
    #pragma unroll
    for (int ta = 0; ta < 4; ++ta) {
        #pragma unroll
        for (int tb = 0; tb < 4; ++tb) {
            #pragma unroll
            for (int i = 0; i < 4; ++i) {
                float e;
                if (ta < 3) e = __expf(S[ta][tb][i] * scale);
                else        e = (quad == 0 && i == 0)
                                ? __expf(S[ta][tb][i] * scale) : 0.0f;  // k=48 only
                S[ta][tb][i] = e;
                psum[tb] += e;
            }
        }
    }
    #pragma unroll
    for (int tb = 0; tb < 4; ++tb) {
        float s = psum[tb];
        s += __shfl_xor(s, 16);
        s += __shfl_xor(s, 32);
        psum[tb] = 1.0f / s;
    }

    // pack P^T to bf16 pairs: pkv[ta][tb][hh] = (P[2hh], P[2hh+1])
    uint32_t pkv[4][4][2];
    #pragma unroll
    for (int ta = 0; ta < 4; ++ta) {
        #pragma unroll
        for (int tb = 0; tb < 4; ++tb) {
            #pragma unroll
            for (int hh = 0; hh < 2; ++hh) {
                float lo = S[ta][tb][2 * hh]     * psum[tb];
                float hi = S[ta][tb][2 * hh + 1] * psum[tb];
                asm("v_cvt_pk_bf16_f32 %0, %1, %2"
                    : "=v"(pkv[ta][tb][hh]) : "v"(lo), "v"(hi));
            }
        }
    }

    // ---- PV: O^T[d][q] = mfma(V^T_frag, P^T_frag) ----
    // B-frag (tb,kk) elem e: j = kk*32+quad*8+e, from lane (quad&1)*32+lr (+16
    // for e>=4), array pkv[kk*2 + (quad>=2)][tb][(e&3)>>1 pair].
    const int lo_lane = (quad & 1) * 32 + lr;
    const bool hiq = quad >= 2;
    floatx4 Ot[2][4] = {};
    #pragma unroll
    for (int kk = 0; kk < 2; ++kk) {
        uint4 pfr[4];
        #pragma unroll
        for (int tb = 0; tb < 4; ++tb) {
            uint32_t a0 = (uint32_t)__shfl((int)pkv[kk * 2][tb][0],     lo_lane);
            uint32_t b0 = (uint32_t)__shfl((int)pkv[kk * 2 + 1][tb][0], lo_lane);
            uint32_t a1 = (uint32_t)__shfl((int)pkv[kk * 2][tb][1],     lo_lane);
            uint32_t b1 = (uint32_t)__shfl((int)pkv[kk * 2 + 1][tb][1], lo_lane);
            uint32_t a2 = (uint32_t)__shfl((int)pkv[kk * 2][tb][0],     lo_lane + 16);
            uint32_t b2 = (uint32_t)__shfl((int)pkv[kk * 2 + 1][tb][0], lo_lane + 16);
            uint32_t a3 = (uint32_t)__shfl((int)pkv[kk * 2][tb][1],     lo_lane + 16);
            uint32_t b3 = (uint32_t)__shfl((int)pkv[kk * 2 + 1][tb][1], lo_lane + 16);
            pfr[tb] = uint4{hiq ? b0 : a0, hiq ? b1 : a1,
                            hiq ? b2 : a2, hiq ? b3 : a3};
        }
        bf16x8 vf[2];
        #pragma unroll
        for (int td = 0; td < 2; ++td)
            vf[td] = *(const bf16x8*)&Vt[(td * 16 + lr) * PLD + kk * 32 + quad * 8];
        #pragma unroll
        for (int td = 0; td < 2; ++td)
            #pragma unroll
            for (int tb = 0; tb < 4; ++tb)
                Ot[td][tb] = __builtin_amdgcn_mfma_f32_16x16x32_bf16(
                    vf[td], as_bf8(pfr[tb]), Ot[td][tb], 0, 0, 0);
    }

    // ---- fused depthwise 3x3 conv: convb[j][c] over 49 tokens x 32 ch ----
    // Vt is dead after PV (same-wave DS ordering); reuse it as convb [49][32].
    uint16_t* convb = Vt;
    #pragma unroll
    for (int it = 0; it < 4; ++it) {
        int u = it * 64 + lane;                      // (token j, 8-ch group g)
        if (u < 196) {
            int j = u >> 2, g = u & 3;
            int py = j / 7, px = j % 7;
            float acc[8];
            {
                float4 b0 = *(const float4*)(warr + 288 + g * 8);
                float4 b1 = *(const float4*)(warr + 288 + g * 8 + 4);
                acc[0] = b0.x; acc[1] = b0.y; acc[2] = b0.z; acc[3] = b0.w;
                acc[4] = b1.x; acc[5] = b1.y; acc[6] = b1.z; acc[7] = b1.w;
            }
            #pragma unroll
            for (int ky = 0; ky < 3; ++ky) {
                #pragma unroll
                for (int kx = 0; kx < 3; ++kx) {
                    int hrow = (py + ky) * 9 + (px + kx);
                    U16x8 v; v.u = *(const uint4*)&Vhalo[hrow * 32 + g * 8];
                    const float* wp = warr + (ky * 3 + kx) * 32 + g * 8;
                    float4 w0 = *(const float4*)wp;
                    float4 w1 = *(const float4*)(wp + 4);
                    acc[0] += bf2f(v.h[0]) * w0.x;
                    acc[1] += bf2f(v.h[1]) * w0.y;
                    acc[2] += bf2f(v.h[2]) * w0.z;
                    acc[3] += bf2f(v.h[3]) * w0.w;
                    acc[4] += bf2f(v.h[4]) * w1.x;
                    acc[5] += bf2f(v.h[5]) * w1.y;
                    acc[6] += bf2f(v.h[6]) * w1.z;
                    acc[7] += bf2f(v.h[7]) * w1.w;
                }
            }
            U16x8 rr;
            #pragma unroll
            for (int q = 0; q < 8; ++q) rr.h[q] = f2bf(acc[q]);
            *(uint4*)&convb[j * 32 + g * 8] = rr.u;
        }
    }

    // ---- epilogue: y[q][d] = Ot[td][tb][i] + conv; q=tb*16+lr, d=td*16+quad*4+i
    #pragma unroll
    for (int tb = 0; tb < 4; ++tb) {
        int q = tb * 16 + lr;
        if (q < 49) {
            int py = q / 7, px = q % 7;
            int n = (wy * 7 + py) * IMW + wx * 7 + px;
            uint16_t* dst = y + (size_t)(b * NTOK + n) * DIMC + h * 32;
            #pragma unroll
            for (int td = 0; td < 2; ++td) {
                int d0 = td * 16 + quad * 4;
                uint2 cv = *(const uint2*)&convb[q * 32 + d0];
                float o0 = Ot[td][tb][0] + bf2f((uint16_t)(cv.x & 0xffffu));
                float o1 = Ot[td][tb][1] + bf2f((uint16_t)(cv.x >> 16));
                float o2 = Ot[td][tb][2] + bf2f((uint16_t)(cv.y & 0xffffu));
                float o3 = Ot[td][tb][3] + bf2f((uint16_t)(cv.y >> 16));
                uint32_t w0, w1;
                asm("v_cvt_pk_bf16_f32 %0, %1, %2" : "=v"(w0) : "v"(o0), "v"(o1));
                asm("v_cvt_pk_bf16_f32 %0, %1, %2" : "=v"(w1) : "v"(o2), "v"(o3));
                *(uint2*)(dst + d0) = uint2{w0, w1};
            }
        }
    }
}

// ---------------- launch ----------------
extern "C" void kernel_launch(void* const* d_in, const int* in_sizes, int n_in,
                              void* d_out, int out_size, void* d_ws, size_t ws_size,
                              hipStream_t stream)
{
    const float* x      = (const float*)d_in[0];
    const float* w_qkv  = (const float*)d_in[1];
    const float* w_proj = (const float*)d_in[2];
    const float* b_proj = (const float*)d_in[3];
    const float* w_conv = (const float*)d_in[4];
    const float* b_conv = (const float*)d_in[5];
    float* out = (float*)d_out;

    // ws layout (155.3 MB):
    //  [0, 115605504)              qkv bf16 (50176 x 1152)
    //  [115605504, +38535168)      xb bf16 (50176 x 384), reused as y bf16 after GEMM1
    //  then wqkvT bf16 (1152x384), wprojT bf16 (384x384)
    char* ws = (char*)d_ws;
    uint16_t* qkv    = (uint16_t*)ws;
    uint16_t* xb     = (uint16_t*)(ws + 115605504);
    uint16_t* yb     = xb;  // alias: xb dead after GEMM1
    uint16_t* wqkvT  = (uint16_t*)(ws + 115605504 + 38535168);
    uint16_t* wprojT = wqkvT + QKVLD * GK;

    // prep (fused: cvt + both weight transposes)
    prep_kernel<<<dim3(CVTB + TQKVB + TPRJB), 256, 0, stream>>>(
        x, xb, w_qkv, wqkvT, w_proj, wprojT);

    // 1) qkv = xb @ w_qkv   (M=50176, N=1152), bf16 out  [256x128 tile, padded]
    gemm_bt<false><<<dim3(MTILES_PAD * (QKVLD / 128)), 512, 0, stream>>>(
        xb, wqkvT, nullptr, qkv, QKVLD);

    // 2) MFMA windowed attention + fused depthwise conv -> y (bf16)
    attn_mfma<<<dim3(BATCH * 64 * HEADS / 2), 128, 0, stream>>>(
        qkv, w_conv, b_conv, yb);

    // 3) out = y @ w_proj + b_proj (M=50176, N=384), fp32 out  [256x128 tile]
    gemm_bt<true><<<dim3(MTILES_PAD * (DIMC / 128)), 512, 0, stream>>>(
        yb, wprojT, b_proj, out, DIMC);
}

// Round 7
// 297.658 us; speedup vs baseline: 1.5591x; 1.0109x over previous
//
#include <hip/hip_runtime.h>
#include <cstdint>
#include <cstddef>

typedef __bf16 bf16x8 __attribute__((ext_vector_type(8)));
typedef float floatx4 __attribute__((ext_vector_type(4)));

#define DEV static __device__ __forceinline__

DEV float bf2f(uint16_t u) {
    union { uint32_t i; float f; } x; x.i = ((uint32_t)u) << 16; return x.f;
}
DEV uint16_t f2bf(float f) {
    uint32_t u = __float_as_uint(f);
    uint32_t r = (u + 0x7FFFu + ((u >> 16) & 1u)) >> 16;   // RNE
    return (uint16_t)r;
}
DEV bf16x8 as_bf8(uint4 u) {
    union { uint4 u; bf16x8 b; } c; c.u = u; return c.b;
}
// async global->LDS, 16B per lane. LDS dest must be wave-uniform base (+lane*16 by HW).
DEV void g2l16(const void* g, void* l) {
    __builtin_amdgcn_global_load_lds(
        (const __attribute__((address_space(1))) void*)g,
        (__attribute__((address_space(3))) void*)l, 16, 0, 0);
}

union U16x8 { uint16_t h[8]; uint4 u; };

// ---------------- problem constants ----------------
constexpr int DIMC  = 384;
constexpr int HEADS = 12;
constexpr int IMH   = 56, IMW = 56;
constexpr int NTOK  = IMH * IMW;        // 3136
constexpr int BATCH = 16;
constexpr int MTOT  = BATCH * NTOK;     // 50176
constexpr int QKVLD = 3 * DIMC;         // 1152
constexpr int GK    = 384;              // K for both GEMMs

// ---------------- fused prep: cvt x -> bf16, transpose both weights -------
constexpr int CVTB  = (MTOT * DIMC) / (8 * 256);     // 9408
constexpr int TQKVB = (GK * QKVLD) / 256;            // 1728
constexpr int TPRJB = (GK * DIMC) / 256;             // 576

__global__ __launch_bounds__(256) void prep_kernel(
    const float* __restrict__ x,      uint16_t* __restrict__ xb,
    const float* __restrict__ w_qkv,  uint16_t* __restrict__ wqkvT,
    const float* __restrict__ w_proj, uint16_t* __restrict__ wprojT)
{
    int bid = blockIdx.x;
    int t   = threadIdx.x;
    if (bid < CVTB) {
        size_t i = ((size_t)bid * 256 + t) * 8;
        float4 a = *(const float4*)(x + i);
        float4 b = *(const float4*)(x + i + 4);
        U16x8 o;
        o.h[0] = f2bf(a.x); o.h[1] = f2bf(a.y); o.h[2] = f2bf(a.z); o.h[3] = f2bf(a.w);
        o.h[4] = f2bf(b.x); o.h[5] = f2bf(b.y); o.h[6] = f2bf(b.z); o.h[7] = f2bf(b.w);
        *(uint4*)(xb + i) = o.u;
    } else if (bid < CVTB + TQKVB) {
        int idx = (bid - CVTB) * 256 + t;            // idx = c*GK + r
        int r = idx % GK, c = idx / GK;
        wqkvT[idx] = f2bf(w_qkv[(size_t)r * QKVLD + c]);
    } else {
        int idx = (bid - CVTB - TQKVB) * 256 + t;
        int r = idx % GK, c = idx / GK;
        wprojT[idx] = f2bf(w_proj[(size_t)r * DIMC + c]);
    }
}

// ---------------- GEMM: C[M,N] = A[M,K=384] @ Bt[N,K]^T ----
// 128x128 tile, 4 waves (verified R2 skeleton) + depth-2 prefetch with
// COUNTED vmcnt across raw s_barrier (T4): 3 LDS buffers; at step k stage
// tile k+2, compute tile k, then wait vmcnt(4) (tile k+1 landed; tile k+2's
// 4 loads stay in flight across the barrier). sched_barrier(0) pins MFMAs
// (and their lgkm waits) before the barrier -> buf WAR across waves is safe.
// 1D grid with M-supertile-8 XCD swizzle (392 M-tiles, %8==0).
template<bool CF32>
__global__ __launch_bounds__(256) void gemm_bt(const uint16_t* __restrict__ A,
                                               const uint16_t* __restrict__ Bt,
                                               const float* __restrict__ bias,
                                               void* __restrict__ Cptr,
                                               int N)
{
    __shared__ __align__(16) uint16_t sA[3][128 * 32];   // 24 KB
    __shared__ __align__(16) uint16_t sB[3][128 * 32];   // 24 KB

    const int t    = threadIdx.x;
    const int NB   = N >> 7;                       // N-tiles (9 or 3)
    const int bid  = blockIdx.x;
    const int chunk = bid / (8 * NB);
    const int r     = bid % (8 * NB);
    const int bm    = chunk * 8 + (r & 7);
    const int bn    = r >> 3;
    const int wave = t >> 6, lane = t & 63;
    const int wm   = (wave >> 1) * 64, wn = (wave & 1) * 64;
    const int lr   = lane & 15, quad = lane >> 4;

    // staging: thread t covers row t>>2 (call1) / 64+(t>>2) (call2), 8 elems at (t&3)*8
    const uint16_t* Ag = A  + (size_t)(bm * 128 + (t >> 2)) * GK + (t & 3) * 8;
    const uint16_t* Bg = Bt + (size_t)(bn * 128 + (t >> 2)) * GK + (t & 3) * 8;

    auto stage = [&](int buf, int k0) {
        g2l16(Ag + k0, sA[buf] + wave * 512);
        g2l16(Ag + (size_t)64 * GK + k0, sA[buf] + 2048 + wave * 512);
        g2l16(Bg + k0, sB[buf] + wave * 512);
        g2l16(Bg + (size_t)64 * GK + k0, sB[buf] + 2048 + wave * 512);
    };

    floatx4 acc[4][4] = {};

    auto compute = [&](int buf) {
        bf16x8 af[4], bfr[4];
        #pragma unroll
        for (int mt = 0; mt < 4; ++mt)
            af[mt] = *(const bf16x8*)&sA[buf][(wm + mt * 16 + lr) * 32 + quad * 8];
        #pragma unroll
        for (int nt = 0; nt < 4; ++nt)
            bfr[nt] = *(const bf16x8*)&sB[buf][(wn + nt * 16 + lr) * 32 + quad * 8];
        #pragma unroll
        for (int mt = 0; mt < 4; ++mt)
            #pragma unroll
            for (int nt = 0; nt < 4; ++nt)
                acc[mt][nt] = __builtin_amdgcn_mfma_f32_16x16x32_bf16(
                    af[mt], bfr[nt], acc[mt][nt], 0, 0, 0);
    };

    // prologue: tiles 0 and 1 in flight; wait for tile 0 only (vmcnt 4 = tile1's loads)
    stage(0, 0);
    stage(1, 32);
    asm volatile("s_waitcnt vmcnt(4)" ::: "memory");
    __builtin_amdgcn_sched_barrier(0);
    __builtin_amdgcn_s_barrier();
    __builtin_amdgcn_sched_barrier(0);

#define K_STEP(K, DOPRE, VM)                                   \
    {                                                          \
        if (DOPRE) stage((K + 2) % 3, (K + 2) * 32);           \
        compute(K % 3);                                        \
        asm volatile("s_waitcnt vmcnt(" VM ")" ::: "memory");  \
        __builtin_amdgcn_sched_barrier(0);                     \
        __builtin_amdgcn_s_barrier();                          \
        __builtin_amdgcn_sched_barrier(0);                     \
    }

    K_STEP(0, 1, "4")
    K_STEP(1, 1, "4")
    K_STEP(2, 1, "4")
    K_STEP(3, 1, "4")
    K_STEP(4, 1, "4")
    K_STEP(5, 1, "4")
    K_STEP(6, 1, "4")
    K_STEP(7, 1, "4")
    K_STEP(8, 1, "4")
    K_STEP(9, 1, "4")
    K_STEP(10, 0, "0")
    compute(11 % 3);   // last tile; nothing outstanding
#undef K_STEP

    // epilogue: C/D layout col=lane&15, row=quad*4+reg
    #pragma unroll
    for (int mt = 0; mt < 4; ++mt) {
        #pragma unroll
        for (int nt = 0; nt < 4; ++nt) {
            int gc = bn * 128 + wn + nt * 16 + lr;
            float bv = bias ? bias[gc] : 0.0f;
            int gr0 = bm * 128 + wm + mt * 16 + quad * 4;
            #pragma unroll
            for (int i = 0; i < 4; ++i) {
                if constexpr (CF32) {
                    ((float*)Cptr)[(size_t)(gr0 + i) * N + gc] = acc[mt][nt][i] + bv;
                } else {
                    ((uint16_t*)Cptr)[(size_t)(gr0 + i) * N + gc] = f2bf(acc[mt][nt][i] + bv);
                }
            }
        }
    }
}

// ---------------- MFMA windowed attention + fused depthwise conv ----------
// one wave per (b, window, head); 2 waves / 128-thread block; no barriers.
// Swapped-operand scheme: S^T = mfma(K,Q) so softmax k-dim is register-local
// (2 shfl_xor per q-tile); P^T stays in registers (cvt_pk bf16 pairs) and PV
// B-fragments are built via lane shuffles -> NO Pbuf in LDS.
// LDS/wave: Vt 32x72 (reused as convb after PV) | Vhalo 81x32 | warr 320 f32.
constexpr int PLD = 72;   // padded row stride (bf16 elems)
constexpr int WAVE_ELEMS = 32 * PLD + 81 * 32;   // 2304 + 2592 = 4896

__global__ __launch_bounds__(128) void attn_mfma(const uint16_t* __restrict__ qkv,
                                                 const float* __restrict__ wconv,
                                                 const float* __restrict__ bconv,
                                                 uint16_t* __restrict__ y)
{
    __shared__ uint16_t lds[2][WAVE_ELEMS];
    __shared__ float    warr_all[2][320];

    const int wave = threadIdx.x >> 6;
    const int lane = threadIdx.x & 63;
    const int unit = blockIdx.x * 2 + wave;          // 0..12287
    const int h  = unit % HEADS;
    const int w  = (unit / HEADS) & 63;
    const int b  = unit / (HEADS * 64);
    const int wy = w >> 3, wx = w & 7;
    const int lr = lane & 15, quad = lane >> 4;

    uint16_t* Vt    = lds[wave];                     // [32][PLD]
    uint16_t* Vhalo = lds[wave] + 32 * PLD;          // [81][32]
    float*    warr  = warr_all[wave];                // [0,288) weights, [288,320) bias

    // ---- stage conv weights + bias ----
    #pragma unroll
    for (int it = 0; it < 5; ++it) {
        int idx = it * 64 + lane;
        if (idx < 288) warr[idx] = wconv[(idx >> 5) * DIMC + h * 32 + (idx & 31)];
    }
    if (lane < 32) warr[288 + lane] = bconv[h * 32 + lane];

    // ---- stage V halo: Vhalo[hy*9+hx][0..31], zero outside image ----
    #pragma unroll
    for (int it = 0; it < 6; ++it) {
        int u = it * 16 + (lane >> 2);               // halo token 0..95
        int g = lane & 3;
        if (u < 81) {
            int hy = u / 9, hx = u % 9;
            int iy = wy * 7 + hy - 1, ix = wx * 7 + hx - 1;
            uint4 val{0, 0, 0, 0};
            if (iy >= 0 && iy < IMH && ix >= 0 && ix < IMW)
                val = *(const uint4*)(qkv + (size_t)(b * NTOK + iy * IMW + ix) * QKVLD
                                      + 2 * DIMC + h * 32 + g * 8);
            *(uint4*)&Vhalo[u * 32 + g * 8] = val;
        }
    }

    auto rowbase = [&](int i, int which) -> const uint16_t* {
        int py = i / 7, px = i % 7;
        int n = (wy * 7 + py) * IMW + wx * 7 + px;
        return qkv + (size_t)(b * NTOK + n) * QKVLD + which * DIMC + h * 32;
    };

    uint4 qf[4], kf[4];
    #pragma unroll
    for (int tm = 0; tm < 4; ++tm) {
        int i = tm * 16 + lr;
        if (i < 49) {
            qf[tm] = *(const uint4*)(rowbase(i, 0) + quad * 8);
            kf[tm] = *(const uint4*)(rowbase(i, 1) + quad * 8);
        } else {
            qf[tm] = uint4{0, 0, 0, 0};
            kf[tm] = uint4{0, 0, 0, 0};
        }
    }

    {   // build Vt[d][j] (transposed window V) from Vhalo
        int j = lane;
        if (j < 49) {
            int hrow = (j / 7 + 1) * 9 + (j % 7 + 1);
            #pragma unroll
            for (int p = 0; p < 4; ++p) {
                U16x8 tmp; tmp.u = *(const uint4*)&Vhalo[hrow * 32 + p * 8];
                #pragma unroll
                for (int q = 0; q < 8; ++q) Vt[(p * 8 + q) * PLD + j] = tmp.h[q];
            }
        } else {
            #pragma unroll
            for (int d = 0; d < 32; ++d) Vt[d * PLD + j] = 0;
        }
    }

    // ---- S^T[k][q] = mfma(K, Q): row k = ta*16+quad*4+i, col q = tb*16+lr
    floatx4 S[4][4] = {};
    #pragma unroll
    for (int ta = 0; ta < 4; ++ta)
        #pragma unroll
        for (int tb = 0; tb < 4; ++tb)
            S[ta][tb] = __builtin_amdgcn_mfma_f32_16x16x32_bf16(
                as_bf8(kf[ta]), as_bf8(qf[tb]), S[ta][tb], 0, 0, 0);

    // ---- softmax over k (register-local 16 values + cross-quad reduce) ----
    const float scale = 0.17677669529663687f;  // 32^-0.5
    float psum[4] = {0.f, 0.f, 0.f, 0.f};
    #pragma unroll
    for (int ta = 0; ta < 4; ++ta) {
        #pragma unroll
        for (int tb = 0; tb < 4; ++tb) {
            #pragma unroll
            for (int i = 0; i < 4; ++i) {
                float e;
                if (ta < 3) e = __expf(S[ta][tb][i] * scale);
                else        e = (quad == 0 && i == 0)
                                ? __expf(S[ta][tb][i] * scale) : 0.0f;  // k=48 only
                S[ta][tb][i] = e;
                psum[tb] += e;
            }
        }
    }
    #pragma unroll
    for (int tb = 0; tb < 4; ++tb) {
        float s = psum[tb];
        s += __shfl_xor(s, 16);
        s += __shfl_xor(s, 32);
        psum[tb] = 1.0f / s;
    }

    // pack P^T to bf16 pairs: pkv[ta][tb][hh] = (P[2hh], P[2hh+1])
    uint32_t pkv[4][4][2];
    #pragma unroll
    for (int ta = 0; ta < 4; ++ta) {
        #pragma unroll
        for (int tb = 0; tb < 4; ++tb) {
            #pragma unroll
            for (int hh = 0; hh < 2; ++hh) {
                float lo = S[ta][tb][2 * hh]     * psum[tb];
                float hi = S[ta][tb][2 * hh + 1] * psum[tb];
                asm("v_cvt_pk_bf16_f32 %0, %1, %2"
                    : "=v"(pkv[ta][tb][hh]) : "v"(lo), "v"(hi));
            }
        }
    }

    // ---- PV: O^T[d][q] = mfma(V^T_frag, P^T_frag) ----
    // B-frag (tb,kk) elem e: j = kk*32+quad*8+e, from lane (quad&1)*32+lr (+16
    // for e>=4), array pkv[kk*2 + (quad>=2)][tb][(e&3)>>1 pair].
    const int lo_lane = (quad & 1) * 32 + lr;
    const bool hiq = quad >= 2;
    floatx4 Ot[2][4] = {};
    #pragma unroll
    for (int kk = 0; kk < 2; ++kk) {
        uint4 pfr[4];
        #pragma unroll
        for (int tb = 0; tb < 4; ++tb) {
            uint32_t a0 = (uint32_t)__shfl((int)pkv[kk * 2][tb][0],     lo_lane);
            uint32_t b0 = (uint32_t)__shfl((int)pkv[kk * 2 + 1][tb][0], lo_lane);
            uint32_t a1 = (uint32_t)__shfl((int)pkv[kk * 2][tb][1],     lo_lane);
            uint32_t b1 = (uint32_t)__shfl((int)pkv[kk * 2 + 1][tb][1], lo_lane);
            uint32_t a2 = (uint32_t)__shfl((int)pkv[kk * 2][tb][0],     lo_lane + 16);
            uint32_t b2 = (uint32_t)__shfl((int)pkv[kk * 2 + 1][tb][0], lo_lane + 16);
            uint32_t a3 = (uint32_t)__shfl((int)pkv[kk * 2][tb][1],     lo_lane + 16);
            uint32_t b3 = (uint32_t)__shfl((int)pkv[kk * 2 + 1][tb][1], lo_lane + 16);
            pfr[tb] = uint4{hiq ? b0 : a0, hiq ? b1 : a1,
                            hiq ? b2 : a2, hiq ? b3 : a3};
        }
        bf16x8 vf[2];
        #pragma unroll
        for (int td = 0; td < 2; ++td)
            vf[td] = *(const bf16x8*)&Vt[(td * 16 + lr) * PLD + kk * 32 + quad * 8];
        #pragma unroll
        for (int td = 0; td < 2; ++td)
            #pragma unroll
            for (int tb = 0; tb < 4; ++tb)
                Ot[td][tb] = __builtin_amdgcn_mfma_f32_16x16x32_bf16(
                    vf[td], as_bf8(pfr[tb]), Ot[td][tb], 0, 0, 0);
    }

    // ---- fused depthwise 3x3 conv: convb[j][c] over 49 tokens x 32 ch ----
    // Vt is dead after PV (same-wave DS ordering); reuse it as convb [49][32].
    uint16_t* convb = Vt;
    #pragma unroll
    for (int it = 0; it < 4; ++it) {
        int u = it * 64 + lane;                      // (token j, 8-ch group g)
        if (u < 196) {
            int j = u >> 2, g = u & 3;
            int py = j / 7, px = j % 7;
            float acc[8];
            {
                float4 b0 = *(const float4*)(warr + 288 + g * 8);
                float4 b1 = *(const float4*)(warr + 288 + g * 8 + 4);
                acc[0] = b0.x; acc[1] = b0.y; acc[2] = b0.z; acc[3] = b0.w;
                acc[4] = b1.x; acc[5] = b1.y; acc[6] = b1.z; acc[7] = b1.w;
            }
            #pragma unroll
            for (int ky = 0; ky < 3; ++ky) {
                #pragma unroll
                for (int kx = 0; kx < 3; ++kx) {
                    int hrow = (py + ky) * 9 + (px + kx);
                    U16x8 v; v.u = *(const uint4*)&Vhalo[hrow * 32 + g * 8];
                    const float* wp = warr + (ky * 3 + kx) * 32 + g * 8;
                    float4 w0 = *(const float4*)wp;
                    float4 w1 = *(const float4*)(wp + 4);
                    acc[0] += bf2f(v.h[0]) * w0.x;
                    acc[1] += bf2f(v.h[1]) * w0.y;
                    acc[2] += bf2f(v.h[2]) * w0.z;
                    acc[3] += bf2f(v.h[3]) * w0.w;
                    acc[4] += bf2f(v.h[4]) * w1.x;
                    acc[5] += bf2f(v.h[5]) * w1.y;
                    acc[6] += bf2f(v.h[6]) * w1.z;
                    acc[7] += bf2f(v.h[7]) * w1.w;
                }
            }
            U16x8 rr;
            #pragma unroll
            for (int q = 0; q < 8; ++q) rr.h[q] = f2bf(acc[q]);
            *(uint4*)&convb[j * 32 + g * 8] = rr.u;
        }
    }

    // ---- epilogue: y[q][d] = Ot[td][tb][i] + conv; q=tb*16+lr, d=td*16+quad*4+i
    #pragma unroll
    for (int tb = 0; tb < 4; ++tb) {
        int q = tb * 16 + lr;
        if (q < 49) {
            int py = q / 7, px = q % 7;
            int n = (wy * 7 + py) * IMW + wx * 7 + px;
            uint16_t* dst = y + (size_t)(b * NTOK + n) * DIMC + h * 32;
            #pragma unroll
            for (int td = 0; td < 2; ++td) {
                int d0 = td * 16 + quad * 4;
                uint2 cv = *(const uint2*)&convb[q * 32 + d0];
                float o0 = Ot[td][tb][0] + bf2f((uint16_t)(cv.x & 0xffffu));
                float o1 = Ot[td][tb][1] + bf2f((uint16_t)(cv.x >> 16));
                float o2 = Ot[td][tb][2] + bf2f((uint16_t)(cv.y & 0xffffu));
                float o3 = Ot[td][tb][3] + bf2f((uint16_t)(cv.y >> 16));
                uint32_t w0, w1;
                asm("v_cvt_pk_bf16_f32 %0, %1, %2" : "=v"(w0) : "v"(o0), "v"(o1));
                asm("v_cvt_pk_bf16_f32 %0, %1, %2" : "=v"(w1) : "v"(o2), "v"(o3));
                *(uint2*)(dst + d0) = uint2{w0, w1};
            }
        }
    }
}

// ---------------- launch ----------------
extern "C" void kernel_launch(void* const* d_in, const int* in_sizes, int n_in,
                              void* d_out, int out_size, void* d_ws, size_t ws_size,
                              hipStream_t stream)
{
    const float* x      = (const float*)d_in[0];
    const float* w_qkv  = (const float*)d_in[1];
    const float* w_proj = (const float*)d_in[2];
    const float* b_proj = (const float*)d_in[3];
    const float* w_conv = (const float*)d_in[4];
    const float* b_conv = (const float*)d_in[5];
    float* out = (float*)d_out;

    // ws layout (155.3 MB):
    //  [0, 115605504)              qkv bf16 (50176 x 1152)
    //  [115605504, +38535168)      xb bf16 (50176 x 384), reused as y bf16 after GEMM1
    //  then wqkvT bf16 (1152x384), wprojT bf16 (384x384)
    char* ws = (char*)d_ws;
    uint16_t* qkv    = (uint16_t*)ws;
    uint16_t* xb     = (uint16_t*)(ws + 115605504);
    uint16_t* yb     = xb;  // alias: xb dead after GEMM1
    uint16_t* wqkvT  = (uint16_t*)(ws + 115605504 + 38535168);
    uint16_t* wprojT = wqkvT + QKVLD * GK;

    // prep (fused: cvt + both weight transposes)
    prep_kernel<<<dim3(CVTB + TQKVB + TPRJB), 256, 0, stream>>>(
        x, xb, w_qkv, wqkvT, w_proj, wprojT);

    // 1) qkv = xb @ w_qkv   (M=50176, N=1152), bf16 out  [128^2, counted-vmcnt]
    gemm_bt<false><<<dim3((MTOT / 128) * (QKVLD / 128)), 256, 0, stream>>>(
        xb, wqkvT, nullptr, qkv, QKVLD);

    // 2) MFMA windowed attention + fused depthwise conv -> y (bf16)
    attn_mfma<<<dim3(BATCH * 64 * HEADS / 2), 128, 0, stream>>>(
        qkv, w_conv, b_conv, yb);

    // 3) out = y @ w_proj + b_proj (M=50176, N=384), fp32 out  [128^2]
    gemm_bt<true><<<dim3((MTOT / 128) * (DIMC / 128)), 256, 0, stream>>>(
        yb, wprojT, b_proj, out, DIMC);
}